// Round 5
// baseline (488.601 us; speedup 1.0000x reference)
//
#include <hip/hip_runtime.h>
#include <hip/hip_bf16.h>

typedef __attribute__((ext_vector_type(8))) short short8;
typedef __attribute__((ext_vector_type(4))) float floatx4;

#define NB 4
#define GRIDD 128
#define GRID3 (128*128*128)
#define C 128
#define KSLOT 32
#define CTX_BPB 256
#define DEN_BLK 1024
#define STAT_BLK 1024
#define PCAP 8192

static __device__ __forceinline__ unsigned short f2bf(float f){
  unsigned u = __builtin_bit_cast(unsigned, f);
  unsigned r = (u + 0x7FFFu + ((u >> 16) & 1u)) >> 16;
  return (unsigned short)r;
}
static __device__ __forceinline__ float bf2f(unsigned short h){
  unsigned u = ((unsigned)h) << 16;
  return __builtin_bit_cast(float, u);
}

// ---------- prep: bf16 conversions + transposes + grid-hash scatter ----------
__global__ void prepk(const float* __restrict__ feats, const float* __restrict__ convw,
                      const float* __restrict__ inw, const int* __restrict__ coords,
                      unsigned short* __restrict__ Fb, unsigned short* __restrict__ Wt,
                      unsigned short* __restrict__ Wq, unsigned short* __restrict__ WkvT,
                      int* __restrict__ gh, long total1)
{
  const long stride = (long)gridDim.x * blockDim.x;
  const long i0 = (long)blockIdx.x * blockDim.x + threadIdx.x;
  const long q4 = total1 >> 2;
  const float4* f4 = reinterpret_cast<const float4*>(feats);
  ushort4* fb4 = reinterpret_cast<ushort4*>(Fb);
  for (long i = i0; i < q4; i += stride){
    const float4 v = f4[i];
    ushort4 o; o.x = f2bf(v.x); o.y = f2bf(v.y); o.z = f2bf(v.z); o.w = f2bf(v.w);
    fb4[i] = o;
  }
  for (long i = i0; i < 27L*C*C; i += stride){
    long k = i >> 14; long r = (i >> 7) & 127; long c = i & 127;
    Wt[i] = f2bf(convw[(k << 14) + (c << 7) + r]);
  }
  for (long i = i0; i < C*C; i += stride) Wq[i] = f2bf(inw[i]);
  for (long i = i0; i < 2L*C*C; i += stride){
    long which = i >> 14, rem = i & 16383, ii = rem >> 7, cout = rem & 127;
    WkvT[i] = f2bf(inw[((1 + which) << 14) + (cout << 7) + ii]);
  }
  // scatter active sites into dense grid hash (grid NOT pre-cleared)
  const long nsites = total1 >> 7;
  for (long i = i0; i < nsites; i += stride){
    const int4 cr = *reinterpret_cast<const int4*>(coords + i * 4);
    gh[(((cr.x*GRIDD + cr.y)*GRIDD + cr.z)*GRIDD) + cr.w] = (int)i;
  }
}

// ---------- fold W2 = (bw[:, :128]+bw[:, 128:]) @ outw ; b2 = Wcf @ outb ----------
__global__ __launch_bounds__(128) void w2k(const float* __restrict__ bw,
                                           const float* __restrict__ outw,
                                           const float* __restrict__ outb,
                                           unsigned short* __restrict__ W2b,
                                           float* __restrict__ b2){
  const int o = blockIdx.x, i = threadIdx.x;
  __shared__ float wcf[128];
  __shared__ float red[128];
  const float w_i = bw[(size_t)o*256 + i] + bw[(size_t)o*256 + 128 + i];
  wcf[i] = w_i;
  red[i] = w_i * outb[i];
  __syncthreads();
  float acc = 0.f;
  #pragma unroll 8
  for (int j = 0; j < 128; j++) acc = fmaf(wcf[j], outw[j*128 + i], acc);
  W2b[o*128 + i] = f2bf(acc);
  for (int s = 64; s > 0; s >>= 1){
    if (i < s) red[i] += red[i + s];
    __syncthreads();
  }
  if (i == 0) b2[o] = red[0];
}

// ---------- pair lists; coords-validated (garbage-proof), wave-aggregated counts ----------
__global__ __launch_bounds__(256) void pairk(const int* __restrict__ coords,
                                             const int* __restrict__ gh,
                                             int2* __restrict__ pairs,
                                             int* __restrict__ gcnt, int N){
  __shared__ int wcnt[4][27];
  __shared__ int woff[4][27];
  const int t = threadIdx.x, wave = t >> 6, lane = t & 63;
  const int p = blockIdx.x * 256 + t;
  const bool active = p < N;
  int4 cr = make_int4(0, 0, 0, 0);
  if (active) cr = *reinterpret_cast<const int4*>(coords + (size_t)p * 4);
  const int b = cr.x, x = cr.y, y = cr.z, z = cr.w;
  int jl[27];
  #pragma unroll
  for (int k = 0; k < 27; k++){
    jl[k] = -1;
    if (k == 13) continue;
    if (active){
      const int dx = k / 9 - 1, dy = (k / 3) % 3 - 1, dz = k % 3 - 1;
      const int nx = x + dx, ny = y + dy, nz = z + dz;
      if (((unsigned)nx < 128u) & ((unsigned)ny < 128u) & ((unsigned)nz < 128u)){
        const int gi = ((((b << 7) + nx) << 7) + ny) * GRIDD + nz;
        const int jj = gh[gi];
        if ((unsigned)jj < (unsigned)N){
          const int4 cj = *reinterpret_cast<const int4*>(coords + (size_t)jj * 4);
          if (cj.x == b && cj.y == nx && cj.z == ny && cj.w == nz) jl[k] = jj;
        }
      }
    }
  }
  #pragma unroll
  for (int k = 0; k < 27; k++){
    const unsigned long long m = __ballot(jl[k] >= 0);
    if (lane == 0) wcnt[wave][k] = (int)__popcll(m);
  }
  __syncthreads();
  if (t < 27){
    const int c0 = wcnt[0][t], c1 = wcnt[1][t], c2 = wcnt[2][t], c3 = wcnt[3][t];
    const int tot = c0 + c1 + c2 + c3;
    int gb = 0;
    if (t != 13 && tot > 0) gb = atomicAdd(&gcnt[t], tot);
    woff[0][t] = gb;
    woff[1][t] = gb + c0;
    woff[2][t] = gb + c0 + c1;
    woff[3][t] = gb + c0 + c1 + c2;
  }
  __syncthreads();
  const unsigned long long ltm = ((unsigned long long)1 << lane) - 1;
  #pragma unroll
  for (int k = 0; k < 27; k++){
    if (k == 13) continue;
    const unsigned long long m = __ballot(jl[k] >= 0);
    if (jl[k] >= 0){
      const int slot = woff[wave][k] + (int)__popcll(m & ltm);
      if (slot < PCAP) pairs[(size_t)k * PCAP + slot] = make_int2(p, jl[k]);
    }
  }
}

// ---------- off-center scatter-GEMM: Wt[k] in LDS, 16-pair chunks, atomic adds ----------
__global__ __launch_bounds__(256) void scatk(
    const unsigned short* __restrict__ F, const unsigned short* __restrict__ Wt,
    const int2* __restrict__ pairs, const int* __restrict__ gcnt,
    float* __restrict__ X, int N)
{
  __shared__ unsigned short wl[128 * 136];
  const int k = (blockIdx.x < 13) ? blockIdx.x : blockIdx.x + 1;
  const int t = threadIdx.x;
  const unsigned short* wg = Wt + (size_t)k * C * C;
  for (int idx = t; idx < 128 * 16; idx += 256){
    const int row = idx >> 4, seg = idx & 15;
    *reinterpret_cast<short8*>(&wl[row * 136 + seg * 8]) =
        *reinterpret_cast<const short8*>(wg + row * 128 + seg * 8);
  }
  __syncthreads();
  const int cnt = min(gcnt[k], PCAP);
  const int nch = (cnt + 15) >> 4;
  const int wave = t >> 6, lane = t & 63, lo = lane & 15, hi = lane >> 4;
  for (int c = blockIdx.y * 4 + wave; c < nch; c += 32 * 4){
    const int pidx = c * 16 + lo;
    const bool pv = pidx < cnt;
    const int2 pr = pv ? pairs[(size_t)k * PCAP + pidx] : make_int2(0, 0);
    const unsigned short* frow = F + (size_t)pr.y * C;
    short8 a[4];
    #pragma unroll
    for (int kc = 0; kc < 4; kc++){
      a[kc] = *reinterpret_cast<const short8*>(frow + kc * 32 + hi * 8);
      if (!pv) a[kc] = (short8){0,0,0,0,0,0,0,0};
    }
    floatx4 acc[8];
    #pragma unroll
    for (int i = 0; i < 8; i++) acc[i] = (floatx4){0.f,0.f,0.f,0.f};
    #pragma unroll
    for (int kc = 0; kc < 4; kc++){
      const int koff = kc * 32 + hi * 8;
      #pragma unroll
      for (int ct = 0; ct < 8; ct++){
        const short8 b = *reinterpret_cast<const short8*>(&wl[(ct*16 + lo) * 136 + koff]);
        acc[ct] = __builtin_amdgcn_mfma_f32_16x16x32_bf16(a[kc], b, acc[ct], 0, 0, 0);
      }
    }
    #pragma unroll
    for (int i2 = 0; i2 < 4; i2++){
      const int src = hi * 4 + i2;
      const int row = __shfl(pr.x, src);
      if (c * 16 + src < cnt){
        #pragma unroll
        for (int ct = 0; ct < 8; ct++)
          atomicAdd(&X[(size_t)row * C + ct * 16 + lo], acc[ct][i2]);
      }
    }
  }
}

// ---------- merged stats (blocks 0..STAT_BLK-1) + denom (blocks STAT_BLK..) ----------
__global__ __launch_bounds__(256) void sdk(const float* __restrict__ X,
                                           const float* __restrict__ probs,
                                           const int* __restrict__ coords,
                                           float* __restrict__ spgs,
                                           float* __restrict__ dpart, int N){
  __shared__ float ls[256][4];
  __shared__ float lq[256][4];
  const int t = threadIdx.x;
  if (blockIdx.x < STAT_BLK){
    const int blk = blockIdx.x;
    const int c4 = t & 31, rg = t >> 5;
    float s0=0.f,s1=0.f,s2=0.f,s3=0.f, q0=0.f,q1=0.f,q2=0.f,q3=0.f;
    for (int r = blk * 8 + rg; r < N; r += STAT_BLK * 8){
      const float4 v = *reinterpret_cast<const float4*>(X + (size_t)r * C + c4 * 4);
      s0 += v.x; s1 += v.y; s2 += v.z; s3 += v.w;
      q0 = fmaf(v.x, v.x, q0); q1 = fmaf(v.y, v.y, q1);
      q2 = fmaf(v.z, v.z, q2); q3 = fmaf(v.w, v.w, q3);
    }
    ls[t][0]=s0; ls[t][1]=s1; ls[t][2]=s2; ls[t][3]=s3;
    lq[t][0]=q0; lq[t][1]=q1; lq[t][2]=q2; lq[t][3]=q3;
    __syncthreads();
    if (t < 32){
      float as[4]={0.f,0.f,0.f,0.f}, aq[4]={0.f,0.f,0.f,0.f};
      #pragma unroll
      for (int g = 0; g < 8; g++){
        #pragma unroll
        for (int j = 0; j < 4; j++){ as[j] += ls[g*32 + t][j]; aq[j] += lq[g*32 + t][j]; }
      }
      #pragma unroll
      for (int j = 0; j < 4; j++){
        spgs[(size_t)blk * 256 + t*4 + j] = as[j];
        spgs[(size_t)blk * 256 + 128 + t*4 + j] = aq[j];
      }
    }
  } else {
    const int blk = blockIdx.x - STAT_BLK;
    const int k = t & 31, rh = t >> 5;
    float a0 = 0.f, a1 = 0.f, a2 = 0.f, a3 = 0.f;
    for (int r = blk * 8 + rh; r < N; r += DEN_BLK * 8){
      const int b = coords[(size_t)r * 4];
      const float e = __expf(probs[(size_t)r * 32 + k]);
      a0 += (b == 0) ? e : 0.f;
      a1 += (b == 1) ? e : 0.f;
      a2 += (b == 2) ? e : 0.f;
      a3 += (b == 3) ? e : 0.f;
    }
    float (*dls)[128] = reinterpret_cast<float (*)[128]>(&ls[0][0]);
    dls[rh][0*32 + k] = a0; dls[rh][1*32 + k] = a1;
    dls[rh][2*32 + k] = a2; dls[rh][3*32 + k] = a3;
    __syncthreads();
    if (t < 128){
      float s = 0.f;
      #pragma unroll
      for (int j = 0; j < 8; j++) s += dls[j][t];
      dpart[(size_t)blk * 128 + t] = s;
    }
  }
}

// ---------- reduce partials: which=0 gsum, 1 gsq, 2 denom ----------
__global__ __launch_bounds__(128) void reduk(const float* __restrict__ pgs,
                                             const float* __restrict__ dpart,
                                             float* __restrict__ gsum,
                                             float* __restrict__ gsq,
                                             float* __restrict__ denom){
  const int which = blockIdx.x, slice = blockIdx.y, t = threadIdx.x;
  float s = 0.f;
  if (which < 2){
    const float* src = pgs + which * 128 + t;
    for (int j = slice; j < STAT_BLK; j += 8) s += src[(size_t)j * 256];
    atomicAdd((which ? gsq : gsum) + t, s);
  } else {
    const float* src = dpart + t;
    for (int j = slice; j < DEN_BLK; j += 8) s += src[(size_t)j * 128];
    atomicAdd(denom + t, s);
  }
}

// ---------- finalize BN scale/shift + inverse denominators ----------
__global__ void finalizek(const float* __restrict__ sums, const float* __restrict__ sumsq,
                          const float* __restrict__ gamma, const float* __restrict__ beta,
                          const float* __restrict__ denom,
                          float* __restrict__ scalev, float* __restrict__ shiftv,
                          float* __restrict__ invden, int N){
  const int t = threadIdx.x;   // 128
  const float invN = 1.f / (float)N;
  const float mu = sums[t] * invN;
  const float var = sumsq[t] * invN - mu * mu;
  const float sc = gamma[t] * rsqrtf(var + 1e-5f);
  scalev[t] = sc;
  shiftv[t] = beta[t] - mu * sc;
  invden[t] = 1.f / denom[t];
}

// ---------- ctx partials v3: LDS tiles + BN+ReLU inline + writes xb bf16 ----------
__global__ __launch_bounds__(256) void ctx2k(const float* __restrict__ Xm,
                                             const float* __restrict__ probs,
                                             const float* __restrict__ scalev,
                                             const float* __restrict__ shiftv,
                                             float* __restrict__ pbuf,
                                             unsigned short* __restrict__ xb, int NPER){
  __shared__ float xL[32 * 128];       // 16 KB raw x tile
  __shared__ float pe[32 * 32];        // 4 KB exp(probs) tile
  __shared__ float red[2 * KSLOT * C]; // 32 KB reduction
  __shared__ float scL[128], shL[128]; // 1 KB BN params
  const int blk = blockIdx.x;
  const int b = blk >> 8, j = blk & 255;
  const int rows = (NPER + CTX_BPB - 1) / CTX_BPB;
  const int r0 = j * rows;
  const int r1 = min(r0 + rows, NPER);
  const int t = threadIdx.x, c = t & 127, rh = t >> 7;
  if (t < 128){ scL[t] = scalev[t]; shL[t] = shiftv[t]; }
  __syncthreads();
  const float sc = scL[c], sh = shL[c];
  float acc[KSLOT];
  #pragma unroll
  for (int k = 0; k < KSLOT; k++) acc[k] = 0.f;

  const int wr = t >> 3;            // tile row 0..31
  const int wc = (t & 7) * 16;      // col start 0..112

  for (int base = r0; base < r1; base += 32){
    __syncthreads();
    #pragma unroll
    for (int i = 0; i < 4; i++){
      const int idx = i * 256 + t;
      const int r = idx >> 5, c4 = idx & 31;
      const int rr = base + r;
      float4 v = make_float4(0.f, 0.f, 0.f, 0.f);
      if (rr < r1) v = *reinterpret_cast<const float4*>(Xm + ((size_t)b * NPER + rr) * C + c4 * 4);
      *reinterpret_cast<float4*>(&xL[r * 128 + c4 * 4]) = v;
    }
    {
      const int r = t >> 3, k4 = t & 7;
      const int rr = base + r;
      float4 v = make_float4(0.f, 0.f, 0.f, 0.f);
      if (rr < r1){
        const float4 pv = *reinterpret_cast<const float4*>(probs + ((size_t)b * NPER + rr) * 32 + k4 * 4);
        v.x = __expf(pv.x); v.y = __expf(pv.y); v.z = __expf(pv.z); v.w = __expf(pv.w);
      }
      *reinterpret_cast<float4*>(&pe[r * 32 + k4 * 4]) = v;
    }
    __syncthreads();
    {
      const int rr = base + wr;
      if (rr < r1){
        short8 o0, o1;
        #pragma unroll
        for (int jj = 0; jj < 8; jj++){
          o0[jj] = (short)f2bf(fmaxf(fmaf(xL[wr * 128 + wc + jj], scL[wc + jj], shL[wc + jj]), 0.f));
          o1[jj] = (short)f2bf(fmaxf(fmaf(xL[wr * 128 + wc + 8 + jj], scL[wc + 8 + jj], shL[wc + 8 + jj]), 0.f));
        }
        unsigned short* xp = xb + ((size_t)b * NPER + rr) * C + wc;
        *reinterpret_cast<short8*>(xp) = o0;
        *reinterpret_cast<short8*>(xp + 8) = o1;
      }
    }
    const int rend = min(32, r1 - base);
    for (int r = rh; r < rend; r += 2){
      const float xv = fmaxf(fmaf(xL[r * 128 + c], sc, sh), 0.f);
      const float4* wrp = reinterpret_cast<const float4*>(&pe[r * 32]);
      #pragma unroll
      for (int kq = 0; kq < 8; kq++){
        const float4 w4 = wrp[kq];   // wave-broadcast (same addr all lanes)
        acc[kq*4+0] = fmaf(w4.x, xv, acc[kq*4+0]);
        acc[kq*4+1] = fmaf(w4.y, xv, acc[kq*4+1]);
        acc[kq*4+2] = fmaf(w4.z, xv, acc[kq*4+2]);
        acc[kq*4+3] = fmaf(w4.w, xv, acc[kq*4+3]);
      }
    }
  }
  __syncthreads();
  #pragma unroll
  for (int k = 0; k < KSLOT; k++) red[(rh * KSLOT + k) * C + c] = acc[k];
  __syncthreads();
  float* dst = pbuf + (size_t)blk * KSLOT * C;
  for (int i = t; i < KSLOT * C; i += 256) dst[i] = red[i] + red[KSLOT * C + i];
}

// ---------- kv: reduce ctx partials then project ----------
__global__ __launch_bounds__(256) void kvk(const float* __restrict__ pbuf,
                                           const float* __restrict__ invden,
                                           const unsigned short* __restrict__ WkvT,
                                           const float* __restrict__ inb,
                                           float* __restrict__ kh, float* __restrict__ vh){
  __shared__ float rowp[2][C];
  __shared__ float row[C];
  const int bk = blockIdx.x;              // b*32 + k
  const int b = bk >> 5, k = bk & 31;
  const int t = threadIdx.x, c = t & 127, jh = t >> 7;
  float s = 0.f;
  for (int j = jh; j < CTX_BPB; j += 2)
    s += pbuf[((size_t)(b * CTX_BPB + j) * KSLOT + k) * C + c];
  rowp[jh][c] = s;
  __syncthreads();
  if (t < C) row[t] = (rowp[0][t] + rowp[1][t]) * invden[b * KSLOT + k];
  __syncthreads();
  const int which = t >> 7;
  const unsigned short* W = WkvT + (size_t)which * C * C;
  float acc = inb[(1 + which) * C + c];
  #pragma unroll 8
  for (int i = 0; i < C; i++) acc = fmaf(row[i], bf2f(W[i * C + c]), acc);
  (which ? vh : kh)[(size_t)bk * C + c] = acc;
}

// ---------- N x 128 @ (128x128)^T bf16 MFMA GEMM (swapped operands: vectorized stores) ----------
__global__ __launch_bounds__(256) void gemm128(
    const unsigned short* __restrict__ A, const unsigned short* __restrict__ W,
    const float* __restrict__ bias, float scale,
    float* __restrict__ outF, unsigned short* __restrict__ outB, int N)
{
  const int tid = threadIdx.x;
  const int wave = tid >> 6, lane = tid & 63;
  const int rbase = blockIdx.x * 64 + (wave >> 1) * 32;
  const int cbase = (wave & 1) * 64;
  const int lo = lane & 15, hi = lane >> 4;
  floatx4 acc[2][4];
  #pragma unroll
  for (int rt = 0; rt < 2; rt++)
    #pragma unroll
    for (int ct = 0; ct < 4; ct++) acc[rt][ct] = (floatx4){0.f,0.f,0.f,0.f};
  const int m0 = rbase + lo, m1 = rbase + 16 + lo;
  const int m0c = m0 < N ? m0 : N - 1;
  const int m1c = m1 < N ? m1 : N - 1;
  #pragma unroll
  for (int kc = 0; kc < 4; kc++){
    const int koff = kc * 32 + hi * 8;
    const short8 a0 = *reinterpret_cast<const short8*>(A + (size_t)m0c * C + koff);
    const short8 a1 = *reinterpret_cast<const short8*>(A + (size_t)m1c * C + koff);
    #pragma unroll
    for (int ct = 0; ct < 4; ct++){
      const int n = cbase + ct * 16 + lo;
      const short8 b = *reinterpret_cast<const short8*>(W + (size_t)n * C + koff);
      acc[0][ct] = __builtin_amdgcn_mfma_f32_16x16x32_bf16(b, a0, acc[0][ct], 0, 0, 0);
      acc[1][ct] = __builtin_amdgcn_mfma_f32_16x16x32_bf16(b, a1, acc[1][ct], 0, 0, 0);
    }
  }
  #pragma unroll
  for (int rt = 0; rt < 2; rt++){
    const int row = rbase + rt * 16 + lo;
    if (row < N){
      #pragma unroll
      for (int ct = 0; ct < 4; ct++){
        const int col = cbase + ct * 16 + hi * 4;
        float4 bv = make_float4(0.f, 0.f, 0.f, 0.f);
        if (bias) bv = *reinterpret_cast<const float4*>(bias + col);
        float4 v;
        v.x = (acc[rt][ct][0] + bv.x) * scale;
        v.y = (acc[rt][ct][1] + bv.y) * scale;
        v.z = (acc[rt][ct][2] + bv.z) * scale;
        v.w = (acc[rt][ct][3] + bv.w) * scale;
        if (outF) *reinterpret_cast<float4*>(outF + (size_t)row * C + col) = v;
        if (outB){
          ushort4 u;
          u.x = f2bf(v.x); u.y = f2bf(v.y); u.z = f2bf(v.z); u.w = f2bf(v.w);
          *reinterpret_cast<ushort4*>(outB + (size_t)row * C + col) = u;
        }
      }
    }
  }
}

// ---------- fused attention: q-proj (MFMA) + v3b attention + out-proj (MFMA) ----------
__global__ __launch_bounds__(256) void attn4k(
    const unsigned short* __restrict__ xb,   // [NB*NPER][C] bf16 relu(bn(x))
    const unsigned short* __restrict__ wq,   // [128][128] bf16 (row = out col)
    const float* __restrict__ inb,           // inb[0..127] = bq
    const unsigned short* __restrict__ w2,   // folded W2 bf16
    const float* __restrict__ b2,            // [128]
    const float* __restrict__ kh, const float* __restrict__ vh,
    float* __restrict__ out, int NPER)
{
  __shared__ float khL[KSLOT * C];          // 16 KB
  __shared__ float vhL[KSLOT * C];          // 16 KB
  __shared__ unsigned short qL[64 * 136];   // 17 KB (pad 136: 16B-aligned rows)
  __shared__ unsigned short oL[64 * 136];   // 17 KB
  const int t = threadIdx.x;
  const int b = blockIdx.y;
  const int n0 = blockIdx.x * 64;
  // stage K/V
  {
    const float4* ks = reinterpret_cast<const float4*>(kh + (size_t)b * KSLOT * C);
    const float4* vs = reinterpret_cast<const float4*>(vh + (size_t)b * KSLOT * C);
    float4* kd = reinterpret_cast<float4*>(khL);
    float4* vd = reinterpret_cast<float4*>(vhL);
    #pragma unroll
    for (int i = 0; i < 4; i++){ kd[i * 256 + t] = ks[i * 256 + t]; vd[i * 256 + t] = vs[i * 256 + t]; }
  }
  // q phase: q = (xb @ Wq^T + bq) * 0.25 -> qL (bf16), proven gemm128 pattern
  const int wave = t >> 6, lane = t & 63;
  const int rb = (wave >> 1) * 32, cb = (wave & 1) * 64;
  const int lo = lane & 15, hi = lane >> 4;
  {
    floatx4 qa[2][4];
    #pragma unroll
    for (int rt = 0; rt < 2; rt++)
      #pragma unroll
      for (int ct = 0; ct < 4; ct++) qa[rt][ct] = (floatx4){0.f,0.f,0.f,0.f};
    const unsigned short* A = xb + (size_t)b * NPER * C;
    const int m0 = n0 + rb + lo, m1 = n0 + rb + 16 + lo;
    const int m0c = m0 < NPER ? m0 : NPER - 1;
    const int m1c = m1 < NPER ? m1 : NPER - 1;
    #pragma unroll
    for (int kc = 0; kc < 4; kc++){
      const int koff = kc * 32 + hi * 8;
      const short8 a0 = *reinterpret_cast<const short8*>(A + (size_t)m0c * C + koff);
      const short8 a1 = *reinterpret_cast<const short8*>(A + (size_t)m1c * C + koff);
      #pragma unroll
      for (int ct = 0; ct < 4; ct++){
        const int n = cb + ct * 16 + lo;
        const short8 w = *reinterpret_cast<const short8*>(wq + (size_t)n * C + koff);
        qa[0][ct] = __builtin_amdgcn_mfma_f32_16x16x32_bf16(w, a0, qa[0][ct], 0, 0, 0);
        qa[1][ct] = __builtin_amdgcn_mfma_f32_16x16x32_bf16(w, a1, qa[1][ct], 0, 0, 0);
      }
    }
    #pragma unroll
    for (int rt = 0; rt < 2; rt++){
      const int row = rb + rt * 16 + lo;
      #pragma unroll
      for (int ct = 0; ct < 4; ct++){
        const int col = cb + ct * 16 + hi * 4;
        const float4 bv = *reinterpret_cast<const float4*>(inb + col);
        ushort4 u;
        u.x = f2bf((qa[rt][ct][0] + bv.x) * 0.25f);
        u.y = f2bf((qa[rt][ct][1] + bv.y) * 0.25f);
        u.z = f2bf((qa[rt][ct][2] + bv.z) * 0.25f);
        u.w = f2bf((qa[rt][ct][3] + bv.w) * 0.25f);
        *reinterpret_cast<ushort4*>(&qL[row * 136 + col]) = u;
      }
    }
  }
  __syncthreads();
  // attention phase (v3b body; q from qL, o -> oL)
  const int h = t >> 5, p = t & 31;
  for (int g = 0; g < 2; g++){
    const int r = g * 32 + p;
    float qv[16];
    {
      const short8* qp = reinterpret_cast<const short8*>(&qL[r * 136 + h * 16]);
      const short8 qa2 = qp[0], qc2 = qp[1];
      #pragma unroll
      for (int i = 0; i < 8; i++){
        qv[i]     = bf2f((unsigned short)qa2[i]);
        qv[8 + i] = bf2f((unsigned short)qc2[i]);
      }
    }
    float sv[KSLOT];
    #pragma unroll
    for (int k = 0; k < KSLOT; k++){
      const float4* kp = reinterpret_cast<const float4*>(&khL[k * C + h * 16]);
      const float4 k0 = kp[0], k1 = kp[1], k2 = kp[2], k3 = kp[3];
      float s;
      s = qv[0] * k0.x;
      s = fmaf(qv[1], k0.y, s);  s = fmaf(qv[2],  k0.z, s);  s = fmaf(qv[3],  k0.w, s);
      s = fmaf(qv[4], k1.x, s);  s = fmaf(qv[5],  k1.y, s);  s = fmaf(qv[6],  k1.z, s);
      s = fmaf(qv[7], k1.w, s);  s = fmaf(qv[8],  k2.x, s);  s = fmaf(qv[9],  k2.y, s);
      s = fmaf(qv[10], k2.z, s); s = fmaf(qv[11], k2.w, s);  s = fmaf(qv[12], k3.x, s);
      s = fmaf(qv[13], k3.y, s); s = fmaf(qv[14], k3.z, s);  s = fmaf(qv[15], k3.w, s);
      sv[k] = s;
    }
    float m = sv[0];
    #pragma unroll
    for (int k = 1; k < KSLOT; k++) m = fmaxf(m, sv[k]);
    float sum = 0.f;
    #pragma unroll
    for (int k = 0; k < KSLOT; k++){ const float e = __expf(sv[k] - m); sv[k] = e; sum += e; }
    const float inv = 1.f / sum;
    float o[16];
    #pragma unroll
    for (int i = 0; i < 16; i++) o[i] = 0.f;
    #pragma unroll
    for (int k = 0; k < KSLOT; k++){
      const float w = sv[k];
      const float4* vp = reinterpret_cast<const float4*>(&vhL[k * C + h * 16]);
      const float4 v0 = vp[0], v1 = vp[1], v2 = vp[2], v3 = vp[3];
      o[0]  = fmaf(w, v0.x, o[0]);  o[1]  = fmaf(w, v0.y, o[1]);
      o[2]  = fmaf(w, v0.z, o[2]);  o[3]  = fmaf(w, v0.w, o[3]);
      o[4]  = fmaf(w, v1.x, o[4]);  o[5]  = fmaf(w, v1.y, o[5]);
      o[6]  = fmaf(w, v1.z, o[6]);  o[7]  = fmaf(w, v1.w, o[7]);
      o[8]  = fmaf(w, v2.x, o[8]);  o[9]  = fmaf(w, v2.y, o[9]);
      o[10] = fmaf(w, v2.z, o[10]); o[11] = fmaf(w, v2.w, o[11]);
      o[12] = fmaf(w, v3.x, o[12]); o[13] = fmaf(w, v3.y, o[13]);
      o[14] = fmaf(w, v3.z, o[14]); o[15] = fmaf(w, v3.w, o[15]);
    }
    {
      short8 s0, s1;
      #pragma unroll
      for (int i = 0; i < 8; i++){
        s0[i] = (short)f2bf(o[i] * inv);
        s1[i] = (short)f2bf(o[8 + i] * inv);
      }
      *reinterpret_cast<short8*>(&oL[r * 136 + h * 16]) = s0;
      *reinterpret_cast<short8*>(&oL[r * 136 + h * 16 + 8]) = s1;
    }
  }
  __syncthreads();
  // out-proj phase: out = oL @ W2^T + b2 (f32 stores)
  {
    floatx4 oa[2][4];
    #pragma unroll
    for (int rt = 0; rt < 2; rt++)
      #pragma unroll
      for (int ct = 0; ct < 4; ct++) oa[rt][ct] = (floatx4){0.f,0.f,0.f,0.f};
    #pragma unroll
    for (int kc = 0; kc < 4; kc++){
      const int koff = kc * 32 + hi * 8;
      const short8 a0 = *reinterpret_cast<const short8*>(&oL[(rb + lo) * 136 + koff]);
      const short8 a1 = *reinterpret_cast<const short8*>(&oL[(rb + 16 + lo) * 136 + koff]);
      #pragma unroll
      for (int ct = 0; ct < 4; ct++){
        const int n = cb + ct * 16 + lo;
        const short8 w = *reinterpret_cast<const short8*>(w2 + (size_t)n * C + koff);
        oa[0][ct] = __builtin_amdgcn_mfma_f32_16x16x32_bf16(w, a0, oa[0][ct], 0, 0, 0);
        oa[1][ct] = __builtin_amdgcn_mfma_f32_16x16x32_bf16(w, a1, oa[1][ct], 0, 0, 0);
      }
    }
    #pragma unroll
    for (int rt = 0; rt < 2; rt++){
      const int row = n0 + rb + rt * 16 + lo;
      if (row < NPER){
        #pragma unroll
        for (int ct = 0; ct < 4; ct++){
          const int col = cb + ct * 16 + hi * 4;
          const float4 bv = *reinterpret_cast<const float4*>(b2 + col);
          float4 v;
          v.x = oa[rt][ct][0] + bv.x;
          v.y = oa[rt][ct][1] + bv.y;
          v.z = oa[rt][ct][2] + bv.z;
          v.w = oa[rt][ct][3] + bv.w;
          *reinterpret_cast<float4*>(out + ((size_t)b * NPER + row) * C + col) = v;
        }
      }
    }
  }
}

extern "C" void kernel_launch(void* const* d_in, const int* in_sizes, int n_in,
                              void* d_out, int out_size, void* d_ws, size_t ws_size,
                              hipStream_t stream){
  const float* feats  = (const float*)d_in[0];
  const float* probs  = (const float*)d_in[1];
  const float* convw  = (const float*)d_in[2];
  const float* gamma  = (const float*)d_in[3];
  const float* beta   = (const float*)d_in[4];
  const float* inw    = (const float*)d_in[5];
  const float* inb    = (const float*)d_in[6];
  const float* outw   = (const float*)d_in[7];
  const float* outb   = (const float*)d_in[8];
  const float* bw     = (const float*)d_in[9];
  const int*   coords = (const int*)d_in[10];
  const int N = in_sizes[0] / C;
  const int NPER = N / NB;
  const int NBLK = (N + 63) / 64;

  char* ws = (char*)d_ws;
  size_t off = 0;
  auto alloc = [&](size_t bytes) -> char* {
    char* r = ws + off; off += (bytes + 255) & ~(size_t)255; return r;
  };
  int* grid_h            = (int*)alloc((size_t)NB * GRID3 * 4);          // 33.5 MB (no memset)
  unsigned short* featsb = (unsigned short*)alloc((size_t)N * C * 2);    // 25.6 MB
  unsigned short* convwt = (unsigned short*)alloc((size_t)27 * C * C * 2);
  unsigned short* wq     = (unsigned short*)alloc((size_t)C * C * 2);
  unsigned short* wkvT   = (unsigned short*)alloc((size_t)2 * C * C * 2);
  unsigned short* w2b    = (unsigned short*)alloc((size_t)C * C * 2);
  float* b2              = (float*)alloc(512);
  float* xconv           = (float*)alloc((size_t)N * C * 4);             // 51.2 MB
  unsigned short* xb     = (unsigned short*)alloc((size_t)N * C * 2);    // 25.6 MB BN+ReLU(x) bf16
  int2* pairs            = (int2*)alloc((size_t)27 * PCAP * 8);          // 1.7 MB
  float* spgs            = (float*)alloc((size_t)STAT_BLK * 256 * 4);    // 1 MB
  float* dpart           = (float*)alloc((size_t)DEN_BLK * 128 * 4);     // 0.5 MB
  float* zero_base       = (float*)alloc((size_t)512 * 4);
  float* gsum   = zero_base;
  float* gsq    = zero_base + 128;
  float* denom  = zero_base + 256;
  int*   gcnt   = (int*)(zero_base + 384);
  float* invden = (float*)alloc(512);
  float* scalev = (float*)alloc(512);
  float* shiftv = (float*)alloc(512);
  float* kh     = (float*)alloc((size_t)NB * KSLOT * C * 4);
  float* vh     = (float*)alloc((size_t)NB * KSLOT * C * 4);
  // alias (lifetimes disjoint): grid dead after pairk; pbuf 16.8 <= 33.5 MB OK
  float* pbuf = (float*)grid_h;

  (void)hipMemsetAsync(zero_base, 0, (size_t)512 * 4, stream);
  prepk<<<2048, 256, 0, stream>>>(feats, convw, inw, coords, featsb, convwt, wq, wkvT, grid_h, (long)N * C);
  w2k<<<128, 128, 0, stream>>>(bw, outw, outb, w2b, b2);
  pairk<<<(N + 255) / 256, 256, 0, stream>>>(coords, grid_h, pairs, gcnt, N);
  // grid_h dead; pbuf aliases it
  gemm128<<<NBLK, 256, 0, stream>>>(featsb, convwt + 13 * C * C, nullptr, 1.f, xconv, nullptr, N);
  scatk<<<dim3(26, 32), 256, 0, stream>>>(featsb, convwt, pairs, gcnt, xconv, N);
  sdk<<<STAT_BLK + DEN_BLK, 256, 0, stream>>>(xconv, probs, coords, spgs, dpart, N);
  {
    dim3 rg(3, 8);
    reduk<<<rg, 128, 0, stream>>>(spgs, dpart, gsum, gsq, denom);
  }
  finalizek<<<1, 128, 0, stream>>>(gsum, gsq, gamma, beta, denom, scalev, shiftv, invden, N);
  ctx2k<<<NB * CTX_BPB, 256, 0, stream>>>(xconv, probs, scalev, shiftv, pbuf, xb, NPER);
  kvk<<<NB * KSLOT, 256, 0, stream>>>(pbuf, invden, wkvT, inb, kh, vh);
  dim3 agrid((NPER + 63) / 64, NB);
  attn4k<<<agrid, 256, 0, stream>>>(xb, wq, inb, w2b, b2, kh, vh, (float*)d_out, NPER);
}

// Round 6
// 433.752 us; speedup vs baseline: 1.1265x; 1.1265x over previous
//
#include <hip/hip_runtime.h>
#include <hip/hip_bf16.h>

typedef __attribute__((ext_vector_type(8))) short short8;
typedef __attribute__((ext_vector_type(4))) float floatx4;

#define NB 4
#define GRIDD 128
#define GRID3 (128*128*128)
#define C 128
#define KSLOT 32
#define CTX_BPB 256
#define DEN_BLK 1024
#define STAT_BLK 1024
#define PCAP 8192
#define PREP_BLKS 2048

static __device__ __forceinline__ unsigned short f2bf(float f){
  unsigned u = __builtin_bit_cast(unsigned, f);
  unsigned r = (u + 0x7FFFu + ((u >> 16) & 1u)) >> 16;
  return (unsigned short)r;
}
static __device__ __forceinline__ float bf2f(unsigned short h){
  unsigned u = ((unsigned)h) << 16;
  return __builtin_bit_cast(float, u);
}

// ---------- prep: bf16 conversions + transposes + grid-hash scatter + w2 fold ----------
// blocks [0, PREP_BLKS): grid-stride prep work
// blocks [PREP_BLKS, PREP_BLKS+128): w2 fold (one block per output row)
__global__ void prepk(const float* __restrict__ feats, const float* __restrict__ convw,
                      const float* __restrict__ inw, const int* __restrict__ coords,
                      const float* __restrict__ bw, const float* __restrict__ outw,
                      const float* __restrict__ outb,
                      unsigned short* __restrict__ Fb, unsigned short* __restrict__ Wt,
                      unsigned short* __restrict__ Wq, unsigned short* __restrict__ WkvT,
                      int* __restrict__ gh, unsigned short* __restrict__ W2b,
                      float* __restrict__ b2, long total1)
{
  const int t = threadIdx.x;
  if (blockIdx.x >= PREP_BLKS){
    // ---- w2 fold: W2 = (bw[:, :128]+bw[:, 128:]) @ outw ; b2 = Wcf @ outb ----
    __shared__ float wcf[128];
    __shared__ float red[128];
    const int o = blockIdx.x - PREP_BLKS;
    if (t < 128){
      const float w_i = bw[(size_t)o*256 + t] + bw[(size_t)o*256 + 128 + t];
      wcf[t] = w_i;
      red[t] = w_i * outb[t];
    }
    __syncthreads();
    if (t < 128){
      float acc = 0.f;
      #pragma unroll 8
      for (int j = 0; j < 128; j++) acc = fmaf(wcf[j], outw[j*128 + t], acc);
      W2b[o*128 + t] = f2bf(acc);
    }
    for (int s = 64; s > 0; s >>= 1){
      if (t < s) red[t] += red[t + s];
      __syncthreads();
    }
    if (t == 0) b2[o] = red[0];
    return;
  }
  const long stride = (long)PREP_BLKS * blockDim.x;
  const long i0 = (long)blockIdx.x * blockDim.x + t;
  const long q4 = total1 >> 2;
  const float4* f4 = reinterpret_cast<const float4*>(feats);
  ushort4* fb4 = reinterpret_cast<ushort4*>(Fb);
  for (long i = i0; i < q4; i += stride){
    const float4 v = f4[i];
    ushort4 o; o.x = f2bf(v.x); o.y = f2bf(v.y); o.z = f2bf(v.z); o.w = f2bf(v.w);
    fb4[i] = o;
  }
  for (long i = i0; i < 27L*C*C; i += stride){
    long k = i >> 14; long r = (i >> 7) & 127; long c = i & 127;
    Wt[i] = f2bf(convw[(k << 14) + (c << 7) + r]);
  }
  for (long i = i0; i < C*C; i += stride) Wq[i] = f2bf(inw[i]);
  for (long i = i0; i < 2L*C*C; i += stride){
    long which = i >> 14, rem = i & 16383, ii = rem >> 7, cout = rem & 127;
    WkvT[i] = f2bf(inw[((1 + which) << 14) + (cout << 7) + ii]);
  }
  // scatter active sites into dense grid hash (grid NOT pre-cleared)
  const long nsites = total1 >> 7;
  for (long i = i0; i < nsites; i += stride){
    const int4 cr = *reinterpret_cast<const int4*>(coords + i * 4);
    gh[(((cr.x*GRIDD + cr.y)*GRIDD + cr.z)*GRIDD) + cr.w] = (int)i;
  }
}

// ---------- pair lists; coords-validated (garbage-proof), wave-aggregated counts ----------
__global__ __launch_bounds__(256) void pairk(const int* __restrict__ coords,
                                             const int* __restrict__ gh,
                                             int2* __restrict__ pairs,
                                             int* __restrict__ gcnt, int N){
  __shared__ int wcnt[4][27];
  __shared__ int woff[4][27];
  const int t = threadIdx.x, wave = t >> 6, lane = t & 63;
  const int p = blockIdx.x * 256 + t;
  const bool active = p < N;
  int4 cr = make_int4(0, 0, 0, 0);
  if (active) cr = *reinterpret_cast<const int4*>(coords + (size_t)p * 4);
  const int b = cr.x, x = cr.y, y = cr.z, z = cr.w;
  int jl[27];
  #pragma unroll
  for (int k = 0; k < 27; k++){
    jl[k] = -1;
    if (k == 13) continue;
    if (active){
      const int dx = k / 9 - 1, dy = (k / 3) % 3 - 1, dz = k % 3 - 1;
      const int nx = x + dx, ny = y + dy, nz = z + dz;
      if (((unsigned)nx < 128u) & ((unsigned)ny < 128u) & ((unsigned)nz < 128u)){
        const int gi = ((((b << 7) + nx) << 7) + ny) * GRIDD + nz;
        const int jj = gh[gi];
        if ((unsigned)jj < (unsigned)N){
          const int4 cj = *reinterpret_cast<const int4*>(coords + (size_t)jj * 4);
          if (cj.x == b && cj.y == nx && cj.z == ny && cj.w == nz) jl[k] = jj;
        }
      }
    }
  }
  #pragma unroll
  for (int k = 0; k < 27; k++){
    const unsigned long long m = __ballot(jl[k] >= 0);
    if (lane == 0) wcnt[wave][k] = (int)__popcll(m);
  }
  __syncthreads();
  if (t < 27){
    const int c0 = wcnt[0][t], c1 = wcnt[1][t], c2 = wcnt[2][t], c3 = wcnt[3][t];
    const int tot = c0 + c1 + c2 + c3;
    int gb = 0;
    if (t != 13 && tot > 0) gb = atomicAdd(&gcnt[t], tot);
    woff[0][t] = gb;
    woff[1][t] = gb + c0;
    woff[2][t] = gb + c0 + c1;
    woff[3][t] = gb + c0 + c1 + c2;
  }
  __syncthreads();
  const unsigned long long ltm = ((unsigned long long)1 << lane) - 1;
  #pragma unroll
  for (int k = 0; k < 27; k++){
    if (k == 13) continue;
    const unsigned long long m = __ballot(jl[k] >= 0);
    if (jl[k] >= 0){
      const int slot = woff[wave][k] + (int)__popcll(m & ltm);
      if (slot < PCAP) pairs[(size_t)k * PCAP + slot] = make_int2(p, jl[k]);
    }
  }
}

// ---------- off-center scatter-GEMM: Wt[k] in LDS, 16-pair chunks, atomic adds ----------
__global__ __launch_bounds__(256) void scatk(
    const unsigned short* __restrict__ F, const unsigned short* __restrict__ Wt,
    const int2* __restrict__ pairs, const int* __restrict__ gcnt,
    float* __restrict__ X, int N)
{
  __shared__ unsigned short wl[128 * 136];
  const int k = (blockIdx.x < 13) ? blockIdx.x : blockIdx.x + 1;
  const int t = threadIdx.x;
  const unsigned short* wg = Wt + (size_t)k * C * C;
  for (int idx = t; idx < 128 * 16; idx += 256){
    const int row = idx >> 4, seg = idx & 15;
    *reinterpret_cast<short8*>(&wl[row * 136 + seg * 8]) =
        *reinterpret_cast<const short8*>(wg + row * 128 + seg * 8);
  }
  __syncthreads();
  const int cnt = min(gcnt[k], PCAP);
  const int nch = (cnt + 15) >> 4;
  const int wave = t >> 6, lane = t & 63, lo = lane & 15, hi = lane >> 4;
  for (int c = blockIdx.y * 4 + wave; c < nch; c += 32 * 4){
    const int pidx = c * 16 + lo;
    const bool pv = pidx < cnt;
    const int2 pr = pv ? pairs[(size_t)k * PCAP + pidx] : make_int2(0, 0);
    const unsigned short* frow = F + (size_t)pr.y * C;
    short8 a[4];
    #pragma unroll
    for (int kc = 0; kc < 4; kc++){
      a[kc] = *reinterpret_cast<const short8*>(frow + kc * 32 + hi * 8);
      if (!pv) a[kc] = (short8){0,0,0,0,0,0,0,0};
    }
    floatx4 acc[8];
    #pragma unroll
    for (int i = 0; i < 8; i++) acc[i] = (floatx4){0.f,0.f,0.f,0.f};
    #pragma unroll
    for (int kc = 0; kc < 4; kc++){
      const int koff = kc * 32 + hi * 8;
      #pragma unroll
      for (int ct = 0; ct < 8; ct++){
        const short8 b = *reinterpret_cast<const short8*>(&wl[(ct*16 + lo) * 136 + koff]);
        acc[ct] = __builtin_amdgcn_mfma_f32_16x16x32_bf16(a[kc], b, acc[ct], 0, 0, 0);
      }
    }
    #pragma unroll
    for (int i2 = 0; i2 < 4; i2++){
      const int src = hi * 4 + i2;
      const int row = __shfl(pr.x, src);
      if (c * 16 + src < cnt){
        #pragma unroll
        for (int ct = 0; ct < 8; ct++)
          atomicAdd(&X[(size_t)row * C + ct * 16 + lo], acc[ct][i2]);
      }
    }
  }
}

// ---------- merged stats (blocks 0..STAT_BLK-1) + denom (blocks STAT_BLK..) ----------
__global__ __launch_bounds__(256) void sdk(const float* __restrict__ X,
                                           const float* __restrict__ probs,
                                           const int* __restrict__ coords,
                                           float* __restrict__ spgs,
                                           float* __restrict__ dpart, int N){
  __shared__ float ls[256][4];
  __shared__ float lq[256][4];
  const int t = threadIdx.x;
  if (blockIdx.x < STAT_BLK){
    const int blk = blockIdx.x;
    const int c4 = t & 31, rg = t >> 5;
    float s0=0.f,s1=0.f,s2=0.f,s3=0.f, q0=0.f,q1=0.f,q2=0.f,q3=0.f;
    for (int r = blk * 8 + rg; r < N; r += STAT_BLK * 8){
      const float4 v = *reinterpret_cast<const float4*>(X + (size_t)r * C + c4 * 4);
      s0 += v.x; s1 += v.y; s2 += v.z; s3 += v.w;
      q0 = fmaf(v.x, v.x, q0); q1 = fmaf(v.y, v.y, q1);
      q2 = fmaf(v.z, v.z, q2); q3 = fmaf(v.w, v.w, q3);
    }
    ls[t][0]=s0; ls[t][1]=s1; ls[t][2]=s2; ls[t][3]=s3;
    lq[t][0]=q0; lq[t][1]=q1; lq[t][2]=q2; lq[t][3]=q3;
    __syncthreads();
    if (t < 32){
      float as[4]={0.f,0.f,0.f,0.f}, aq[4]={0.f,0.f,0.f,0.f};
      #pragma unroll
      for (int g = 0; g < 8; g++){
        #pragma unroll
        for (int j = 0; j < 4; j++){ as[j] += ls[g*32 + t][j]; aq[j] += lq[g*32 + t][j]; }
      }
      #pragma unroll
      for (int j = 0; j < 4; j++){
        spgs[(size_t)blk * 256 + t*4 + j] = as[j];
        spgs[(size_t)blk * 256 + 128 + t*4 + j] = aq[j];
      }
    }
  } else {
    const int blk = blockIdx.x - STAT_BLK;
    const int k = t & 31, rh = t >> 5;
    float a0 = 0.f, a1 = 0.f, a2 = 0.f, a3 = 0.f;
    for (int r = blk * 8 + rh; r < N; r += DEN_BLK * 8){
      const int b = coords[(size_t)r * 4];
      const float e = __expf(probs[(size_t)r * 32 + k]);
      a0 += (b == 0) ? e : 0.f;
      a1 += (b == 1) ? e : 0.f;
      a2 += (b == 2) ? e : 0.f;
      a3 += (b == 3) ? e : 0.f;
    }
    float (*dls)[128] = reinterpret_cast<float (*)[128]>(&ls[0][0]);
    dls[rh][0*32 + k] = a0; dls[rh][1*32 + k] = a1;
    dls[rh][2*32 + k] = a2; dls[rh][3*32 + k] = a3;
    __syncthreads();
    if (t < 128){
      float s = 0.f;
      #pragma unroll
      for (int j = 0; j < 8; j++) s += dls[j][t];
      dpart[(size_t)blk * 128 + t] = s;
    }
  }
}

// ---------- reduce partials: which=0 gsum, 1 gsq, 2 denom ----------
__global__ __launch_bounds__(128) void reduk(const float* __restrict__ pgs,
                                             const float* __restrict__ dpart,
                                             float* __restrict__ gsum,
                                             float* __restrict__ gsq,
                                             float* __restrict__ denom){
  const int which = blockIdx.x, slice = blockIdx.y, t = threadIdx.x;
  float s = 0.f;
  if (which < 2){
    const float* src = pgs + which * 128 + t;
    for (int j = slice; j < STAT_BLK; j += 8) s += src[(size_t)j * 256];
    atomicAdd((which ? gsq : gsum) + t, s);
  } else {
    const float* src = dpart + t;
    for (int j = slice; j < DEN_BLK; j += 8) s += src[(size_t)j * 128];
    atomicAdd(denom + t, s);
  }
}

// ---------- finalize BN scale/shift + inverse denominators ----------
__global__ void finalizek(const float* __restrict__ sums, const float* __restrict__ sumsq,
                          const float* __restrict__ gamma, const float* __restrict__ beta,
                          const float* __restrict__ denom,
                          float* __restrict__ scalev, float* __restrict__ shiftv,
                          float* __restrict__ invden, int N){
  const int t = threadIdx.x;   // 128
  const float invN = 1.f / (float)N;
  const float mu = sums[t] * invN;
  const float var = sumsq[t] * invN - mu * mu;
  const float sc = gamma[t] * rsqrtf(var + 1e-5f);
  scalev[t] = sc;
  shiftv[t] = beta[t] - mu * sc;
  invden[t] = 1.f / denom[t];
}

// ---------- ctx partials v3: LDS tiles + BN+ReLU inline + writes xb bf16 ----------
__global__ __launch_bounds__(256) void ctx2k(const float* __restrict__ Xm,
                                             const float* __restrict__ probs,
                                             const float* __restrict__ scalev,
                                             const float* __restrict__ shiftv,
                                             float* __restrict__ pbuf,
                                             unsigned short* __restrict__ xb, int NPER){
  __shared__ float xL[32 * 128];       // 16 KB raw x tile
  __shared__ float pe[32 * 32];        // 4 KB exp(probs) tile
  __shared__ float red[2 * KSLOT * C]; // 32 KB reduction
  __shared__ float scL[128], shL[128]; // 1 KB BN params
  const int blk = blockIdx.x;
  const int b = blk >> 8, j = blk & 255;
  const int rows = (NPER + CTX_BPB - 1) / CTX_BPB;
  const int r0 = j * rows;
  const int r1 = min(r0 + rows, NPER);
  const int t = threadIdx.x, c = t & 127, rh = t >> 7;
  if (t < 128){ scL[t] = scalev[t]; shL[t] = shiftv[t]; }
  __syncthreads();
  const float sc = scL[c], sh = shL[c];
  float acc[KSLOT];
  #pragma unroll
  for (int k = 0; k < KSLOT; k++) acc[k] = 0.f;

  const int wr = t >> 3;            // tile row 0..31
  const int wc = (t & 7) * 16;      // col start 0..112

  for (int base = r0; base < r1; base += 32){
    __syncthreads();
    #pragma unroll
    for (int i = 0; i < 4; i++){
      const int idx = i * 256 + t;
      const int r = idx >> 5, c4 = idx & 31;
      const int rr = base + r;
      float4 v = make_float4(0.f, 0.f, 0.f, 0.f);
      if (rr < r1) v = *reinterpret_cast<const float4*>(Xm + ((size_t)b * NPER + rr) * C + c4 * 4);
      *reinterpret_cast<float4*>(&xL[r * 128 + c4 * 4]) = v;
    }
    {
      const int r = t >> 3, k4 = t & 7;
      const int rr = base + r;
      float4 v = make_float4(0.f, 0.f, 0.f, 0.f);
      if (rr < r1){
        const float4 pv = *reinterpret_cast<const float4*>(probs + ((size_t)b * NPER + rr) * 32 + k4 * 4);
        v.x = __expf(pv.x); v.y = __expf(pv.y); v.z = __expf(pv.z); v.w = __expf(pv.w);
      }
      *reinterpret_cast<float4*>(&pe[r * 32 + k4 * 4]) = v;
    }
    __syncthreads();
    {
      const int rr = base + wr;
      if (rr < r1){
        short8 o0, o1;
        #pragma unroll
        for (int jj = 0; jj < 8; jj++){
          o0[jj] = (short)f2bf(fmaxf(fmaf(xL[wr * 128 + wc + jj], scL[wc + jj], shL[wc + jj]), 0.f));
          o1[jj] = (short)f2bf(fmaxf(fmaf(xL[wr * 128 + wc + 8 + jj], scL[wc + 8 + jj], shL[wc + 8 + jj]), 0.f));
        }
        unsigned short* xp = xb + ((size_t)b * NPER + rr) * C + wc;
        *reinterpret_cast<short8*>(xp) = o0;
        *reinterpret_cast<short8*>(xp + 8) = o1;
      }
    }
    const int rend = min(32, r1 - base);
    for (int r = rh; r < rend; r += 2){
      const float xv = fmaxf(fmaf(xL[r * 128 + c], sc, sh), 0.f);
      const float4* wrp = reinterpret_cast<const float4*>(&pe[r * 32]);
      #pragma unroll
      for (int kq = 0; kq < 8; kq++){
        const float4 w4 = wrp[kq];   // wave-broadcast (same addr all lanes)
        acc[kq*4+0] = fmaf(w4.x, xv, acc[kq*4+0]);
        acc[kq*4+1] = fmaf(w4.y, xv, acc[kq*4+1]);
        acc[kq*4+2] = fmaf(w4.z, xv, acc[kq*4+2]);
        acc[kq*4+3] = fmaf(w4.w, xv, acc[kq*4+3]);
      }
    }
  }
  __syncthreads();
  #pragma unroll
  for (int k = 0; k < KSLOT; k++) red[(rh * KSLOT + k) * C + c] = acc[k];
  __syncthreads();
  float* dst = pbuf + (size_t)blk * KSLOT * C;
  for (int i = t; i < KSLOT * C; i += 256) dst[i] = red[i] + red[KSLOT * C + i];
}

// ---------- kv: reduce ctx partials then project ----------
__global__ __launch_bounds__(256) void kvk(const float* __restrict__ pbuf,
                                           const float* __restrict__ invden,
                                           const unsigned short* __restrict__ WkvT,
                                           const float* __restrict__ inb,
                                           float* __restrict__ kh, float* __restrict__ vh){
  __shared__ float rowp[2][C];
  __shared__ float row[C];
  const int bk = blockIdx.x;              // b*32 + k
  const int b = bk >> 5, k = bk & 31;
  const int t = threadIdx.x, c = t & 127, jh = t >> 7;
  float s = 0.f;
  for (int j = jh; j < CTX_BPB; j += 2)
    s += pbuf[((size_t)(b * CTX_BPB + j) * KSLOT + k) * C + c];
  rowp[jh][c] = s;
  __syncthreads();
  if (t < C) row[t] = (rowp[0][t] + rowp[1][t]) * invden[b * KSLOT + k];
  __syncthreads();
  const int which = t >> 7;
  const unsigned short* W = WkvT + (size_t)which * C * C;
  float acc = inb[(1 + which) * C + c];
  #pragma unroll 8
  for (int i = 0; i < C; i++) acc = fmaf(row[i], bf2f(W[i * C + c]), acc);
  (which ? vh : kh)[(size_t)bk * C + c] = acc;
}

// ---------- N x 128 @ (128x128)^T bf16 MFMA GEMM (swapped operands: vectorized stores) ----------
__global__ __launch_bounds__(256) void gemm128(
    const unsigned short* __restrict__ A, const unsigned short* __restrict__ W,
    const float* __restrict__ bias, float scale,
    float* __restrict__ outF, unsigned short* __restrict__ outB, int N)
{
  const int tid = threadIdx.x;
  const int wave = tid >> 6, lane = tid & 63;
  const int rbase = blockIdx.x * 64 + (wave >> 1) * 32;
  const int cbase = (wave & 1) * 64;
  const int lo = lane & 15, hi = lane >> 4;
  floatx4 acc[2][4];
  #pragma unroll
  for (int rt = 0; rt < 2; rt++)
    #pragma unroll
    for (int ct = 0; ct < 4; ct++) acc[rt][ct] = (floatx4){0.f,0.f,0.f,0.f};
  const int m0 = rbase + lo, m1 = rbase + 16 + lo;
  const int m0c = m0 < N ? m0 : N - 1;
  const int m1c = m1 < N ? m1 : N - 1;
  #pragma unroll
  for (int kc = 0; kc < 4; kc++){
    const int koff = kc * 32 + hi * 8;
    const short8 a0 = *reinterpret_cast<const short8*>(A + (size_t)m0c * C + koff);
    const short8 a1 = *reinterpret_cast<const short8*>(A + (size_t)m1c * C + koff);
    #pragma unroll
    for (int ct = 0; ct < 4; ct++){
      const int n = cbase + ct * 16 + lo;
      const short8 b = *reinterpret_cast<const short8*>(W + (size_t)n * C + koff);
      acc[0][ct] = __builtin_amdgcn_mfma_f32_16x16x32_bf16(b, a0, acc[0][ct], 0, 0, 0);
      acc[1][ct] = __builtin_amdgcn_mfma_f32_16x16x32_bf16(b, a1, acc[1][ct], 0, 0, 0);
    }
  }
  #pragma unroll
  for (int rt = 0; rt < 2; rt++){
    const int row = rbase + rt * 16 + lo;
    if (row < N){
      #pragma unroll
      for (int ct = 0; ct < 4; ct++){
        const int col = cbase + ct * 16 + hi * 4;
        float4 bv = make_float4(0.f, 0.f, 0.f, 0.f);
        if (bias) bv = *reinterpret_cast<const float4*>(bias + col);
        float4 v;
        v.x = (acc[rt][ct][0] + bv.x) * scale;
        v.y = (acc[rt][ct][1] + bv.y) * scale;
        v.z = (acc[rt][ct][2] + bv.z) * scale;
        v.w = (acc[rt][ct][3] + bv.w) * scale;
        if (outF) *reinterpret_cast<float4*>(outF + (size_t)row * C + col) = v;
        if (outB){
          ushort4 u;
          u.x = f2bf(v.x); u.y = f2bf(v.y); u.z = f2bf(v.z); u.w = f2bf(v.w);
          *reinterpret_cast<ushort4*>(outB + (size_t)row * C + col) = u;
        }
      }
    }
  }
}

// ---------- attention v3b (known-good): 64 rows/block, thread owns (row, head) ----------
__global__ __launch_bounds__(256) void attn3k(const unsigned short* __restrict__ qb,
                                              const float* __restrict__ kh,
                                              const float* __restrict__ vh,
                                              unsigned short* __restrict__ ob, int NPER){
  __shared__ float khL[KSLOT * C];
  __shared__ float vhL[KSLOT * C];
  const int t = threadIdx.x;
  const int b = blockIdx.y;
  const int n0 = blockIdx.x * 64;
  {
    const float4* ks = reinterpret_cast<const float4*>(kh + (size_t)b * KSLOT * C);
    const float4* vs = reinterpret_cast<const float4*>(vh + (size_t)b * KSLOT * C);
    float4* kd = reinterpret_cast<float4*>(khL);
    float4* vd = reinterpret_cast<float4*>(vhL);
    #pragma unroll
    for (int i = 0; i < 4; i++){ kd[i * 256 + t] = ks[i * 256 + t]; vd[i * 256 + t] = vs[i * 256 + t]; }
  }
  __syncthreads();
  const int h = t >> 5, p = t & 31;
  for (int g = 0; g < 2; g++){
    const int n = n0 + g * 32 + p;
    const int nc = n < NPER ? n : NPER - 1;
    float qv[16];
    {
      const short8* qp = reinterpret_cast<const short8*>(qb + ((size_t)b * NPER + nc) * C + h * 16);
      const short8 qa = qp[0], qc = qp[1];
      #pragma unroll
      for (int i = 0; i < 8; i++){
        qv[i]     = bf2f((unsigned short)qa[i]);
        qv[8 + i] = bf2f((unsigned short)qc[i]);
      }
    }
    float sv[KSLOT];
    #pragma unroll
    for (int k = 0; k < KSLOT; k++){
      const float4* kp = reinterpret_cast<const float4*>(&khL[k * C + h * 16]);
      const float4 k0 = kp[0], k1 = kp[1], k2 = kp[2], k3 = kp[3];
      float s;
      s = qv[0] * k0.x;
      s = fmaf(qv[1], k0.y, s);  s = fmaf(qv[2],  k0.z, s);  s = fmaf(qv[3],  k0.w, s);
      s = fmaf(qv[4], k1.x, s);  s = fmaf(qv[5],  k1.y, s);  s = fmaf(qv[6],  k1.z, s);
      s = fmaf(qv[7], k1.w, s);  s = fmaf(qv[8],  k2.x, s);  s = fmaf(qv[9],  k2.y, s);
      s = fmaf(qv[10], k2.z, s); s = fmaf(qv[11], k2.w, s);  s = fmaf(qv[12], k3.x, s);
      s = fmaf(qv[13], k3.y, s); s = fmaf(qv[14], k3.z, s);  s = fmaf(qv[15], k3.w, s);
      sv[k] = s;
    }
    float m = sv[0];
    #pragma unroll
    for (int k = 1; k < KSLOT; k++) m = fmaxf(m, sv[k]);
    float sum = 0.f;
    #pragma unroll
    for (int k = 0; k < KSLOT; k++){ const float e = __expf(sv[k] - m); sv[k] = e; sum += e; }
    const float inv = 1.f / sum;
    float o[16];
    #pragma unroll
    for (int i = 0; i < 16; i++) o[i] = 0.f;
    #pragma unroll
    for (int k = 0; k < KSLOT; k++){
      const float w = sv[k];
      const float4* vp = reinterpret_cast<const float4*>(&vhL[k * C + h * 16]);
      const float4 v0 = vp[0], v1 = vp[1], v2 = vp[2], v3 = vp[3];
      o[0]  = fmaf(w, v0.x, o[0]);  o[1]  = fmaf(w, v0.y, o[1]);
      o[2]  = fmaf(w, v0.z, o[2]);  o[3]  = fmaf(w, v0.w, o[3]);
      o[4]  = fmaf(w, v1.x, o[4]);  o[5]  = fmaf(w, v1.y, o[5]);
      o[6]  = fmaf(w, v1.z, o[6]);  o[7]  = fmaf(w, v1.w, o[7]);
      o[8]  = fmaf(w, v2.x, o[8]);  o[9]  = fmaf(w, v2.y, o[9]);
      o[10] = fmaf(w, v2.z, o[10]); o[11] = fmaf(w, v2.w, o[11]);
      o[12] = fmaf(w, v3.x, o[12]); o[13] = fmaf(w, v3.y, o[13]);
      o[14] = fmaf(w, v3.z, o[14]); o[15] = fmaf(w, v3.w, o[15]);
    }
    if (n < NPER){
      short8 s0, s1;
      #pragma unroll
      for (int i = 0; i < 8; i++){
        s0[i] = (short)f2bf(o[i] * inv);
        s1[i] = (short)f2bf(o[8 + i] * inv);
      }
      unsigned short* op = ob + ((size_t)b * NPER + n) * C + h * 16;
      *reinterpret_cast<short8*>(op) = s0;
      *reinterpret_cast<short8*>(op + 8) = s1;
    }
  }
}

extern "C" void kernel_launch(void* const* d_in, const int* in_sizes, int n_in,
                              void* d_out, int out_size, void* d_ws, size_t ws_size,
                              hipStream_t stream){
  const float* feats  = (const float*)d_in[0];
  const float* probs  = (const float*)d_in[1];
  const float* convw  = (const float*)d_in[2];
  const float* gamma  = (const float*)d_in[3];
  const float* beta   = (const float*)d_in[4];
  const float* inw    = (const float*)d_in[5];
  const float* inb    = (const float*)d_in[6];
  const float* outw   = (const float*)d_in[7];
  const float* outb   = (const float*)d_in[8];
  const float* bw     = (const float*)d_in[9];
  const int*   coords = (const int*)d_in[10];
  const int N = in_sizes[0] / C;
  const int NPER = N / NB;
  const int NBLK = (N + 63) / 64;

  char* ws = (char*)d_ws;
  size_t off = 0;
  auto alloc = [&](size_t bytes) -> char* {
    char* r = ws + off; off += (bytes + 255) & ~(size_t)255; return r;
  };
  int* grid_h            = (int*)alloc((size_t)NB * GRID3 * 4);          // 33.5 MB (no memset)
  unsigned short* featsb = (unsigned short*)alloc((size_t)N * C * 2);    // 25.6 MB
  unsigned short* convwt = (unsigned short*)alloc((size_t)27 * C * C * 2);
  unsigned short* wq     = (unsigned short*)alloc((size_t)C * C * 2);
  unsigned short* wkvT   = (unsigned short*)alloc((size_t)2 * C * C * 2);
  unsigned short* w2b    = (unsigned short*)alloc((size_t)C * C * 2);
  float* b2              = (float*)alloc(512);
  float* xconv           = (float*)alloc((size_t)N * C * 4);             // 51.2 MB
  unsigned short* qb     = (unsigned short*)alloc((size_t)N * C * 2);    // 25.6 MB
  unsigned short* xb     = (unsigned short*)alloc((size_t)N * C * 2);    // 25.6 MB BN+ReLU(x) bf16
  int2* pairs            = (int2*)alloc((size_t)27 * PCAP * 8);          // 1.7 MB
  float* spgs            = (float*)alloc((size_t)STAT_BLK * 256 * 4);    // 1 MB
  float* dpart           = (float*)alloc((size_t)DEN_BLK * 128 * 4);     // 0.5 MB
  float* zero_base       = (float*)alloc((size_t)512 * 4);
  float* gsum   = zero_base;
  float* gsq    = zero_base + 128;
  float* denom  = zero_base + 256;
  int*   gcnt   = (int*)(zero_base + 384);
  float* invden = (float*)alloc(512);
  float* scalev = (float*)alloc(512);
  float* shiftv = (float*)alloc(512);
  float* kh     = (float*)alloc((size_t)NB * KSLOT * C * 4);
  float* vh     = (float*)alloc((size_t)NB * KSLOT * C * 4);
  // aliases (lifetimes disjoint):
  float* pbuf = (float*)grid_h;                  // grid dead after pairk; 16.8 <= 33.5 MB OK
  unsigned short* o_bf = featsb;                 // featsb dead after scatk

  (void)hipMemsetAsync(zero_base, 0, (size_t)512 * 4, stream);
  prepk<<<PREP_BLKS + 128, 256, 0, stream>>>(feats, convw, inw, coords, bw, outw, outb,
                                             featsb, convwt, wq, wkvT, grid_h, w2b, b2,
                                             (long)N * C);
  pairk<<<(N + 255) / 256, 256, 0, stream>>>(coords, grid_h, pairs, gcnt, N);
  // grid_h dead; pbuf aliases it
  gemm128<<<NBLK, 256, 0, stream>>>(featsb, convwt + 13 * C * C, nullptr, 1.f, xconv, nullptr, N);
  scatk<<<dim3(26, 32), 256, 0, stream>>>(featsb, convwt, pairs, gcnt, xconv, N);
  sdk<<<STAT_BLK + DEN_BLK, 256, 0, stream>>>(xconv, probs, coords, spgs, dpart, N);
  {
    dim3 rg(3, 8);
    reduk<<<rg, 128, 0, stream>>>(spgs, dpart, gsum, gsq, denom);
  }
  finalizek<<<1, 128, 0, stream>>>(gsum, gsq, gamma, beta, denom, scalev, shiftv, invden, N);
  ctx2k<<<NB * CTX_BPB, 256, 0, stream>>>(xconv, probs, scalev, shiftv, pbuf, xb, NPER);
  kvk<<<NB * KSLOT, 256, 0, stream>>>(pbuf, invden, wkvT, inb, kh, vh);
  gemm128<<<NBLK, 256, 0, stream>>>(xb, wq, inb, 0.25f, nullptr, qb, N);
  dim3 agrid((NPER + 63) / 64, NB);
  attn3k<<<agrid, 256, 0, stream>>>(qb, kh, vh, o_bf, NPER);
  gemm128<<<NBLK, 256, 0, stream>>>(o_bf, w2b, b2, 1.f, (float*)d_out, nullptr, N);
}

// Round 7
// 428.045 us; speedup vs baseline: 1.1415x; 1.0133x over previous
//
#include <hip/hip_runtime.h>
#include <hip/hip_bf16.h>

typedef __attribute__((ext_vector_type(8))) short short8;
typedef __attribute__((ext_vector_type(4))) float floatx4;

#define NB 4
#define GRIDD 128
#define GRID3 (128*128*128)
#define C 128
#define KSLOT 32
#define CTX_BPB 256
#define DEN_BLK 1024
#define STAT_BLK 1024
#define PCAP 8192
#define PREP_BLKS 2048

static __device__ __forceinline__ unsigned short f2bf(float f){
  unsigned u = __builtin_bit_cast(unsigned, f);
  unsigned r = (u + 0x7FFFu + ((u >> 16) & 1u)) >> 16;
  return (unsigned short)r;
}
static __device__ __forceinline__ float bf2f(unsigned short h){
  unsigned u = ((unsigned)h) << 16;
  return __builtin_bit_cast(float, u);
}

// ---------- prep: bf16 conversions + transposes + grid-hash scatter + w2 fold ----------
__global__ void prepk(const float* __restrict__ feats, const float* __restrict__ convw,
                      const float* __restrict__ inw, const int* __restrict__ coords,
                      const float* __restrict__ bw, const float* __restrict__ outw,
                      const float* __restrict__ outb,
                      unsigned short* __restrict__ Fb, unsigned short* __restrict__ Wt,
                      unsigned short* __restrict__ Wq, unsigned short* __restrict__ WkvT,
                      int* __restrict__ gh, unsigned short* __restrict__ W2b,
                      float* __restrict__ b2, long total1)
{
  const int t = threadIdx.x;
  if (blockIdx.x >= PREP_BLKS){
    __shared__ float wcf[128];
    __shared__ float red[128];
    const int o = blockIdx.x - PREP_BLKS;
    if (t < 128){
      const float w_i = bw[(size_t)o*256 + t] + bw[(size_t)o*256 + 128 + t];
      wcf[t] = w_i;
      red[t] = w_i * outb[t];
    }
    __syncthreads();
    if (t < 128){
      float acc = 0.f;
      #pragma unroll 8
      for (int j = 0; j < 128; j++) acc = fmaf(wcf[j], outw[j*128 + t], acc);
      W2b[o*128 + t] = f2bf(acc);
    }
    for (int s = 64; s > 0; s >>= 1){
      if (t < s) red[t] += red[t + s];
      __syncthreads();
    }
    if (t == 0) b2[o] = red[0];
    return;
  }
  const long stride = (long)PREP_BLKS * blockDim.x;
  const long i0 = (long)blockIdx.x * blockDim.x + t;
  const long q4 = total1 >> 2;
  const float4* f4 = reinterpret_cast<const float4*>(feats);
  ushort4* fb4 = reinterpret_cast<ushort4*>(Fb);
  for (long i = i0; i < q4; i += stride){
    const float4 v = f4[i];
    ushort4 o; o.x = f2bf(v.x); o.y = f2bf(v.y); o.z = f2bf(v.z); o.w = f2bf(v.w);
    fb4[i] = o;
  }
  for (long i = i0; i < 27L*C*C; i += stride){
    long k = i >> 14; long r = (i >> 7) & 127; long c = i & 127;
    Wt[i] = f2bf(convw[(k << 14) + (c << 7) + r]);
  }
  for (long i = i0; i < C*C; i += stride) Wq[i] = f2bf(inw[i]);
  for (long i = i0; i < 2L*C*C; i += stride){
    long which = i >> 14, rem = i & 16383, ii = rem >> 7, cout = rem & 127;
    WkvT[i] = f2bf(inw[((1 + which) << 14) + (cout << 7) + ii]);
  }
  const long nsites = total1 >> 7;
  for (long i = i0; i < nsites; i += stride){
    const int4 cr = *reinterpret_cast<const int4*>(coords + i * 4);
    gh[(((cr.x*GRIDD + cr.y)*GRIDD + cr.z)*GRIDD) + cr.w] = (int)i;
  }
}

// ---------- pair lists; coords-validated (garbage-proof), wave-aggregated counts ----------
__global__ __launch_bounds__(256) void pairk(const int* __restrict__ coords,
                                             const int* __restrict__ gh,
                                             int2* __restrict__ pairs,
                                             int* __restrict__ gcnt, int N){
  __shared__ int wcnt[4][27];
  __shared__ int woff[4][27];
  const int t = threadIdx.x, wave = t >> 6, lane = t & 63;
  const int p = blockIdx.x * 256 + t;
  const bool active = p < N;
  int4 cr = make_int4(0, 0, 0, 0);
  if (active) cr = *reinterpret_cast<const int4*>(coords + (size_t)p * 4);
  const int b = cr.x, x = cr.y, y = cr.z, z = cr.w;
  int jl[27];
  #pragma unroll
  for (int k = 0; k < 27; k++){
    jl[k] = -1;
    if (k == 13) continue;
    if (active){
      const int dx = k / 9 - 1, dy = (k / 3) % 3 - 1, dz = k % 3 - 1;
      const int nx = x + dx, ny = y + dy, nz = z + dz;
      if (((unsigned)nx < 128u) & ((unsigned)ny < 128u) & ((unsigned)nz < 128u)){
        const int gi = ((((b << 7) + nx) << 7) + ny) * GRIDD + nz;
        const int jj = gh[gi];
        if ((unsigned)jj < (unsigned)N){
          const int4 cj = *reinterpret_cast<const int4*>(coords + (size_t)jj * 4);
          if (cj.x == b && cj.y == nx && cj.z == ny && cj.w == nz) jl[k] = jj;
        }
      }
    }
  }
  #pragma unroll
  for (int k = 0; k < 27; k++){
    const unsigned long long m = __ballot(jl[k] >= 0);
    if (lane == 0) wcnt[wave][k] = (int)__popcll(m);
  }
  __syncthreads();
  if (t < 27){
    const int c0 = wcnt[0][t], c1 = wcnt[1][t], c2 = wcnt[2][t], c3 = wcnt[3][t];
    const int tot = c0 + c1 + c2 + c3;
    int gb = 0;
    if (t != 13 && tot > 0) gb = atomicAdd(&gcnt[t], tot);
    woff[0][t] = gb;
    woff[1][t] = gb + c0;
    woff[2][t] = gb + c0 + c1;
    woff[3][t] = gb + c0 + c1 + c2;
  }
  __syncthreads();
  const unsigned long long ltm = ((unsigned long long)1 << lane) - 1;
  #pragma unroll
  for (int k = 0; k < 27; k++){
    if (k == 13) continue;
    const unsigned long long m = __ballot(jl[k] >= 0);
    if (jl[k] >= 0){
      const int slot = woff[wave][k] + (int)__popcll(m & ltm);
      if (slot < PCAP) pairs[(size_t)k * PCAP + slot] = make_int2(p, jl[k]);
    }
  }
}

// ---------- off-center scatter-GEMM: Wt[k] in LDS, 16-pair chunks, atomic adds ----------
__global__ __launch_bounds__(256) void scatk(
    const unsigned short* __restrict__ F, const unsigned short* __restrict__ Wt,
    const int2* __restrict__ pairs, const int* __restrict__ gcnt,
    float* __restrict__ X, int N)
{
  __shared__ unsigned short wl[128 * 136];
  const int k = (blockIdx.x < 13) ? blockIdx.x : blockIdx.x + 1;
  const int t = threadIdx.x;
  const unsigned short* wg = Wt + (size_t)k * C * C;
  for (int idx = t; idx < 128 * 16; idx += 256){
    const int row = idx >> 4, seg = idx & 15;
    *reinterpret_cast<short8*>(&wl[row * 136 + seg * 8]) =
        *reinterpret_cast<const short8*>(wg + row * 128 + seg * 8);
  }
  __syncthreads();
  const int cnt = min(gcnt[k], PCAP);
  const int nch = (cnt + 15) >> 4;
  const int wave = t >> 6, lane = t & 63, lo = lane & 15, hi = lane >> 4;
  for (int c = blockIdx.y * 4 + wave; c < nch; c += 32 * 4){
    const int pidx = c * 16 + lo;
    const bool pv = pidx < cnt;
    const int2 pr = pv ? pairs[(size_t)k * PCAP + pidx] : make_int2(0, 0);
    const unsigned short* frow = F + (size_t)pr.y * C;
    short8 a[4];
    #pragma unroll
    for (int kc = 0; kc < 4; kc++){
      a[kc] = *reinterpret_cast<const short8*>(frow + kc * 32 + hi * 8);
      if (!pv) a[kc] = (short8){0,0,0,0,0,0,0,0};
    }
    floatx4 acc[8];
    #pragma unroll
    for (int i = 0; i < 8; i++) acc[i] = (floatx4){0.f,0.f,0.f,0.f};
    #pragma unroll
    for (int kc = 0; kc < 4; kc++){
      const int koff = kc * 32 + hi * 8;
      #pragma unroll
      for (int ct = 0; ct < 8; ct++){
        const short8 b = *reinterpret_cast<const short8*>(&wl[(ct*16 + lo) * 136 + koff]);
        acc[ct] = __builtin_amdgcn_mfma_f32_16x16x32_bf16(a[kc], b, acc[ct], 0, 0, 0);
      }
    }
    #pragma unroll
    for (int i2 = 0; i2 < 4; i2++){
      const int src = hi * 4 + i2;
      const int row = __shfl(pr.x, src);
      if (c * 16 + src < cnt){
        #pragma unroll
        for (int ct = 0; ct < 8; ct++)
          atomicAdd(&X[(size_t)row * C + ct * 16 + lo], acc[ct][i2]);
      }
    }
  }
}

// ---------- merged stats (blocks 0..STAT_BLK-1) + denom (blocks STAT_BLK..) ----------
__global__ __launch_bounds__(256) void sdk(const float* __restrict__ X,
                                           const float* __restrict__ probs,
                                           const int* __restrict__ coords,
                                           float* __restrict__ spgs,
                                           float* __restrict__ dpart, int N){
  __shared__ float ls[256][4];
  __shared__ float lq[256][4];
  const int t = threadIdx.x;
  if (blockIdx.x < STAT_BLK){
    const int blk = blockIdx.x;
    const int c4 = t & 31, rg = t >> 5;
    float s0=0.f,s1=0.f,s2=0.f,s3=0.f, q0=0.f,q1=0.f,q2=0.f,q3=0.f;
    for (int r = blk * 8 + rg; r < N; r += STAT_BLK * 8){
      const float4 v = *reinterpret_cast<const float4*>(X + (size_t)r * C + c4 * 4);
      s0 += v.x; s1 += v.y; s2 += v.z; s3 += v.w;
      q0 = fmaf(v.x, v.x, q0); q1 = fmaf(v.y, v.y, q1);
      q2 = fmaf(v.z, v.z, q2); q3 = fmaf(v.w, v.w, q3);
    }
    ls[t][0]=s0; ls[t][1]=s1; ls[t][2]=s2; ls[t][3]=s3;
    lq[t][0]=q0; lq[t][1]=q1; lq[t][2]=q2; lq[t][3]=q3;
    __syncthreads();
    if (t < 32){
      float as[4]={0.f,0.f,0.f,0.f}, aq[4]={0.f,0.f,0.f,0.f};
      #pragma unroll
      for (int g = 0; g < 8; g++){
        #pragma unroll
        for (int j = 0; j < 4; j++){ as[j] += ls[g*32 + t][j]; aq[j] += lq[g*32 + t][j]; }
      }
      #pragma unroll
      for (int j = 0; j < 4; j++){
        spgs[(size_t)blk * 256 + t*4 + j] = as[j];
        spgs[(size_t)blk * 256 + 128 + t*4 + j] = aq[j];
      }
    }
  } else {
    const int blk = blockIdx.x - STAT_BLK;
    const int k = t & 31, rh = t >> 5;
    float a0 = 0.f, a1 = 0.f, a2 = 0.f, a3 = 0.f;
    for (int r = blk * 8 + rh; r < N; r += DEN_BLK * 8){
      const int b = coords[(size_t)r * 4];
      const float e = __expf(probs[(size_t)r * 32 + k]);
      a0 += (b == 0) ? e : 0.f;
      a1 += (b == 1) ? e : 0.f;
      a2 += (b == 2) ? e : 0.f;
      a3 += (b == 3) ? e : 0.f;
    }
    float (*dls)[128] = reinterpret_cast<float (*)[128]>(&ls[0][0]);
    dls[rh][0*32 + k] = a0; dls[rh][1*32 + k] = a1;
    dls[rh][2*32 + k] = a2; dls[rh][3*32 + k] = a3;
    __syncthreads();
    if (t < 128){
      float s = 0.f;
      #pragma unroll
      for (int j = 0; j < 8; j++) s += dls[j][t];
      dpart[(size_t)blk * 128 + t] = s;
    }
  }
}

// ---------- reduce partials: which=0 gsum, 1 gsq, 2 denom ----------
__global__ __launch_bounds__(128) void reduk(const float* __restrict__ pgs,
                                             const float* __restrict__ dpart,
                                             float* __restrict__ gsum,
                                             float* __restrict__ gsq,
                                             float* __restrict__ denom){
  const int which = blockIdx.x, slice = blockIdx.y, t = threadIdx.x;
  float s = 0.f;
  if (which < 2){
    const float* src = pgs + which * 128 + t;
    for (int j = slice; j < STAT_BLK; j += 8) s += src[(size_t)j * 256];
    atomicAdd((which ? gsq : gsum) + t, s);
  } else {
    const float* src = dpart + t;
    for (int j = slice; j < DEN_BLK; j += 8) s += src[(size_t)j * 128];
    atomicAdd(denom + t, s);
  }
}

// ---------- finalize BN scale/shift + inverse denominators ----------
__global__ void finalizek(const float* __restrict__ sums, const float* __restrict__ sumsq,
                          const float* __restrict__ gamma, const float* __restrict__ beta,
                          const float* __restrict__ denom,
                          float* __restrict__ scalev, float* __restrict__ shiftv,
                          float* __restrict__ invden, int N){
  const int t = threadIdx.x;   // 128
  const float invN = 1.f / (float)N;
  const float mu = sums[t] * invN;
  const float var = sumsq[t] * invN - mu * mu;
  const float sc = gamma[t] * rsqrtf(var + 1e-5f);
  scalev[t] = sc;
  shiftv[t] = beta[t] - mu * sc;
  invden[t] = 1.f / denom[t];
}

// ---------- ctx partials v3: LDS tiles + BN+ReLU inline + writes xb bf16 ----------
__global__ __launch_bounds__(256) void ctx2k(const float* __restrict__ Xm,
                                             const float* __restrict__ probs,
                                             const float* __restrict__ scalev,
                                             const float* __restrict__ shiftv,
                                             float* __restrict__ pbuf,
                                             unsigned short* __restrict__ xb, int NPER){
  __shared__ float xL[32 * 128];       // 16 KB raw x tile
  __shared__ float pe[32 * 32];        // 4 KB exp(probs) tile
  __shared__ float red[2 * KSLOT * C]; // 32 KB reduction
  __shared__ float scL[128], shL[128]; // 1 KB BN params
  const int blk = blockIdx.x;
  const int b = blk >> 8, j = blk & 255;
  const int rows = (NPER + CTX_BPB - 1) / CTX_BPB;
  const int r0 = j * rows;
  const int r1 = min(r0 + rows, NPER);
  const int t = threadIdx.x, c = t & 127, rh = t >> 7;
  if (t < 128){ scL[t] = scalev[t]; shL[t] = shiftv[t]; }
  __syncthreads();
  const float sc = scL[c], sh = shL[c];
  float acc[KSLOT];
  #pragma unroll
  for (int k = 0; k < KSLOT; k++) acc[k] = 0.f;

  const int wr = t >> 3;            // tile row 0..31
  const int wc = (t & 7) * 16;      // col start 0..112

  for (int base = r0; base < r1; base += 32){
    __syncthreads();
    #pragma unroll
    for (int i = 0; i < 4; i++){
      const int idx = i * 256 + t;
      const int r = idx >> 5, c4 = idx & 31;
      const int rr = base + r;
      float4 v = make_float4(0.f, 0.f, 0.f, 0.f);
      if (rr < r1) v = *reinterpret_cast<const float4*>(Xm + ((size_t)b * NPER + rr) * C + c4 * 4);
      *reinterpret_cast<float4*>(&xL[r * 128 + c4 * 4]) = v;
    }
    {
      const int r = t >> 3, k4 = t & 7;
      const int rr = base + r;
      float4 v = make_float4(0.f, 0.f, 0.f, 0.f);
      if (rr < r1){
        const float4 pv = *reinterpret_cast<const float4*>(probs + ((size_t)b * NPER + rr) * 32 + k4 * 4);
        v.x = __expf(pv.x); v.y = __expf(pv.y); v.z = __expf(pv.z); v.w = __expf(pv.w);
      }
      *reinterpret_cast<float4*>(&pe[r * 32 + k4 * 4]) = v;
    }
    __syncthreads();
    {
      const int rr = base + wr;
      if (rr < r1){
        short8 o0, o1;
        #pragma unroll
        for (int jj = 0; jj < 8; jj++){
          o0[jj] = (short)f2bf(fmaxf(fmaf(xL[wr * 128 + wc + jj], scL[wc + jj], shL[wc + jj]), 0.f));
          o1[jj] = (short)f2bf(fmaxf(fmaf(xL[wr * 128 + wc + 8 + jj], scL[wc + 8 + jj], shL[wc + 8 + jj]), 0.f));
        }
        unsigned short* xp = xb + ((size_t)b * NPER + rr) * C + wc;
        *reinterpret_cast<short8*>(xp) = o0;
        *reinterpret_cast<short8*>(xp + 8) = o1;
      }
    }
    const int rend = min(32, r1 - base);
    for (int r = rh; r < rend; r += 2){
      const float xv = fmaxf(fmaf(xL[r * 128 + c], sc, sh), 0.f);
      const float4* wrp = reinterpret_cast<const float4*>(&pe[r * 32]);
      #pragma unroll
      for (int kq = 0; kq < 8; kq++){
        const float4 w4 = wrp[kq];   // wave-broadcast (same addr all lanes)
        acc[kq*4+0] = fmaf(w4.x, xv, acc[kq*4+0]);
        acc[kq*4+1] = fmaf(w4.y, xv, acc[kq*4+1]);
        acc[kq*4+2] = fmaf(w4.z, xv, acc[kq*4+2]);
        acc[kq*4+3] = fmaf(w4.w, xv, acc[kq*4+3]);
      }
    }
  }
  __syncthreads();
  #pragma unroll
  for (int k = 0; k < KSLOT; k++) red[(rh * KSLOT + k) * C + c] = acc[k];
  __syncthreads();
  float* dst = pbuf + (size_t)blk * KSLOT * C;
  for (int i = t; i < KSLOT * C; i += 256) dst[i] = red[i] + red[KSLOT * C + i];
}

// ---------- kv: reduce ctx partials then project ----------
__global__ __launch_bounds__(256) void kvk(const float* __restrict__ pbuf,
                                           const float* __restrict__ invden,
                                           const unsigned short* __restrict__ WkvT,
                                           const float* __restrict__ inb,
                                           float* __restrict__ kh, float* __restrict__ vh){
  __shared__ float rowp[2][C];
  __shared__ float row[C];
  const int bk = blockIdx.x;              // b*32 + k
  const int b = bk >> 5, k = bk & 31;
  const int t = threadIdx.x, c = t & 127, jh = t >> 7;
  float s = 0.f;
  for (int j = jh; j < CTX_BPB; j += 2)
    s += pbuf[((size_t)(b * CTX_BPB + j) * KSLOT + k) * C + c];
  rowp[jh][c] = s;
  __syncthreads();
  if (t < C) row[t] = (rowp[0][t] + rowp[1][t]) * invden[b * KSLOT + k];
  __syncthreads();
  const int which = t >> 7;
  const unsigned short* W = WkvT + (size_t)which * C * C;
  float acc = inb[(1 + which) * C + c];
  #pragma unroll 8
  for (int i = 0; i < C; i++) acc = fmaf(row[i], bf2f(W[i * C + c]), acc);
  (which ? vh : kh)[(size_t)bk * C + c] = acc;
}

// ---------- N x 128 @ (128x128)^T bf16 MFMA GEMM (swapped operands: vectorized stores) ----------
__global__ __launch_bounds__(256) void gemm128(
    const unsigned short* __restrict__ A, const unsigned short* __restrict__ W,
    const float* __restrict__ bias, float scale,
    float* __restrict__ outF, unsigned short* __restrict__ outB, int N)
{
  const int tid = threadIdx.x;
  const int wave = tid >> 6, lane = tid & 63;
  const int rbase = blockIdx.x * 64 + (wave >> 1) * 32;
  const int cbase = (wave & 1) * 64;
  const int lo = lane & 15, hi = lane >> 4;
  floatx4 acc[2][4];
  #pragma unroll
  for (int rt = 0; rt < 2; rt++)
    #pragma unroll
    for (int ct = 0; ct < 4; ct++) acc[rt][ct] = (floatx4){0.f,0.f,0.f,0.f};
  const int m0 = rbase + lo, m1 = rbase + 16 + lo;
  const int m0c = m0 < N ? m0 : N - 1;
  const int m1c = m1 < N ? m1 : N - 1;
  #pragma unroll
  for (int kc = 0; kc < 4; kc++){
    const int koff = kc * 32 + hi * 8;
    const short8 a0 = *reinterpret_cast<const short8*>(A + (size_t)m0c * C + koff);
    const short8 a1 = *reinterpret_cast<const short8*>(A + (size_t)m1c * C + koff);
    #pragma unroll
    for (int ct = 0; ct < 4; ct++){
      const int n = cbase + ct * 16 + lo;
      const short8 b = *reinterpret_cast<const short8*>(W + (size_t)n * C + koff);
      acc[0][ct] = __builtin_amdgcn_mfma_f32_16x16x32_bf16(b, a0, acc[0][ct], 0, 0, 0);
      acc[1][ct] = __builtin_amdgcn_mfma_f32_16x16x32_bf16(b, a1, acc[1][ct], 0, 0, 0);
    }
  }
  #pragma unroll
  for (int rt = 0; rt < 2; rt++){
    const int row = rbase + rt * 16 + lo;
    if (row < N){
      #pragma unroll
      for (int ct = 0; ct < 4; ct++){
        const int col = cbase + ct * 16 + hi * 4;
        float4 bv = make_float4(0.f, 0.f, 0.f, 0.f);
        if (bias) bv = *reinterpret_cast<const float4*>(bias + col);
        float4 v;
        v.x = (acc[rt][ct][0] + bv.x) * scale;
        v.y = (acc[rt][ct][1] + bv.y) * scale;
        v.z = (acc[rt][ct][2] + bv.z) * scale;
        v.w = (acc[rt][ct][3] + bv.w) * scale;
        if (outF) *reinterpret_cast<float4*>(outF + (size_t)row * C + col) = v;
        if (outB){
          ushort4 u;
          u.x = f2bf(v.x); u.y = f2bf(v.y); u.z = f2bf(v.z); u.w = f2bf(v.w);
          *reinterpret_cast<ushort4*>(outB + (size_t)row * C + col) = u;
        }
      }
    }
  }
}

// ---------- attention v5: 2 rows/thread, online softmax over k-tiles of 8 ----------
// K/V float4 loads shared by both rows -> LDS traffic halved vs v3b.
// Tile state va[8]/vb[8] keeps unroll bodies at v3b scale (rule-#20 safe).
__global__ __launch_bounds__(256) void attn5k(const unsigned short* __restrict__ qb,
                                              const float* __restrict__ kh,
                                              const float* __restrict__ vh,
                                              unsigned short* __restrict__ ob, int NPER){
  __shared__ float khL[KSLOT * C];
  __shared__ float vhL[KSLOT * C];
  const int t = threadIdx.x;
  const int b = blockIdx.y;
  const int n0 = blockIdx.x * 64;
  {
    const float4* ks = reinterpret_cast<const float4*>(kh + (size_t)b * KSLOT * C);
    const float4* vs = reinterpret_cast<const float4*>(vh + (size_t)b * KSLOT * C);
    float4* kd = reinterpret_cast<float4*>(khL);
    float4* vd = reinterpret_cast<float4*>(vhL);
    #pragma unroll
    for (int i = 0; i < 4; i++){ kd[i * 256 + t] = ks[i * 256 + t]; vd[i * 256 + t] = vs[i * 256 + t]; }
  }
  __syncthreads();
  const int h = t >> 5, p = t & 31;
  const int na = n0 + p, nb = n0 + 32 + p;
  const int nac = na < NPER ? na : NPER - 1;
  const int nbc = nb < NPER ? nb : NPER - 1;
  float qa[16], qc[16];
  {
    const short8* qpa = reinterpret_cast<const short8*>(qb + ((size_t)b * NPER + nac) * C + h * 16);
    const short8* qpb = reinterpret_cast<const short8*>(qb + ((size_t)b * NPER + nbc) * C + h * 16);
    const short8 a0 = qpa[0], a1 = qpa[1];
    const short8 b0 = qpb[0], b1 = qpb[1];
    #pragma unroll
    for (int i = 0; i < 8; i++){
      qa[i]     = bf2f((unsigned short)a0[i]);
      qa[8 + i] = bf2f((unsigned short)a1[i]);
      qc[i]     = bf2f((unsigned short)b0[i]);
      qc[8 + i] = bf2f((unsigned short)b1[i]);
    }
  }
  float ma = -3.0e38f, mb = -3.0e38f;
  float sa = 0.f, sb = 0.f;
  float oa[16], oc[16];
  #pragma unroll
  for (int i = 0; i < 16; i++){ oa[i] = 0.f; oc[i] = 0.f; }
  for (int tau = 0; tau < 4; tau++){
    float va[8], vb[8];
    #pragma unroll
    for (int kk = 0; kk < 8; kk++){
      const int k = tau * 8 + kk;
      const float4* kp = reinterpret_cast<const float4*>(&khL[k * C + h * 16]);
      const float4 k0 = kp[0], k1 = kp[1], k2 = kp[2], k3 = kp[3];
      float x, y;
      x = qa[0] * k0.x;            y = qc[0] * k0.x;
      x = fmaf(qa[1],  k0.y, x);   y = fmaf(qc[1],  k0.y, y);
      x = fmaf(qa[2],  k0.z, x);   y = fmaf(qc[2],  k0.z, y);
      x = fmaf(qa[3],  k0.w, x);   y = fmaf(qc[3],  k0.w, y);
      x = fmaf(qa[4],  k1.x, x);   y = fmaf(qc[4],  k1.x, y);
      x = fmaf(qa[5],  k1.y, x);   y = fmaf(qc[5],  k1.y, y);
      x = fmaf(qa[6],  k1.z, x);   y = fmaf(qc[6],  k1.z, y);
      x = fmaf(qa[7],  k1.w, x);   y = fmaf(qc[7],  k1.w, y);
      x = fmaf(qa[8],  k2.x, x);   y = fmaf(qc[8],  k2.x, y);
      x = fmaf(qa[9],  k2.y, x);   y = fmaf(qc[9],  k2.y, y);
      x = fmaf(qa[10], k2.z, x);   y = fmaf(qc[10], k2.z, y);
      x = fmaf(qa[11], k2.w, x);   y = fmaf(qc[11], k2.w, y);
      x = fmaf(qa[12], k3.x, x);   y = fmaf(qc[12], k3.x, y);
      x = fmaf(qa[13], k3.y, x);   y = fmaf(qc[13], k3.y, y);
      x = fmaf(qa[14], k3.z, x);   y = fmaf(qc[14], k3.z, y);
      x = fmaf(qa[15], k3.w, x);   y = fmaf(qc[15], k3.w, y);
      va[kk] = x; vb[kk] = y;
    }
    float tma = va[0], tmb = vb[0];
    #pragma unroll
    for (int kk = 1; kk < 8; kk++){ tma = fmaxf(tma, va[kk]); tmb = fmaxf(tmb, vb[kk]); }
    const float ma2 = fmaxf(ma, tma), mb2 = fmaxf(mb, tmb);
    const float fa = __expf(ma - ma2), fb = __expf(mb - mb2);
    ma = ma2; mb = mb2;
    sa *= fa; sb *= fb;
    #pragma unroll
    for (int i = 0; i < 16; i++){ oa[i] *= fa; oc[i] *= fb; }
    #pragma unroll
    for (int kk = 0; kk < 8; kk++){
      const float ea = __expf(va[kk] - ma);
      const float eb = __expf(vb[kk] - mb);
      va[kk] = ea; vb[kk] = eb;
      sa += ea; sb += eb;
    }
    #pragma unroll
    for (int kk = 0; kk < 8; kk++){
      const int k = tau * 8 + kk;
      const float4* vp = reinterpret_cast<const float4*>(&vhL[k * C + h * 16]);
      const float4 v0 = vp[0], v1 = vp[1], v2 = vp[2], v3 = vp[3];
      const float wa = va[kk], wb = vb[kk];
      oa[0]  = fmaf(wa, v0.x, oa[0]);   oc[0]  = fmaf(wb, v0.x, oc[0]);
      oa[1]  = fmaf(wa, v0.y, oa[1]);   oc[1]  = fmaf(wb, v0.y, oc[1]);
      oa[2]  = fmaf(wa, v0.z, oa[2]);   oc[2]  = fmaf(wb, v0.z, oc[2]);
      oa[3]  = fmaf(wa, v0.w, oa[3]);   oc[3]  = fmaf(wb, v0.w, oc[3]);
      oa[4]  = fmaf(wa, v1.x, oa[4]);   oc[4]  = fmaf(wb, v1.x, oc[4]);
      oa[5]  = fmaf(wa, v1.y, oa[5]);   oc[5]  = fmaf(wb, v1.y, oc[5]);
      oa[6]  = fmaf(wa, v1.z, oa[6]);   oc[6]  = fmaf(wb, v1.z, oc[6]);
      oa[7]  = fmaf(wa, v1.w, oa[7]);   oc[7]  = fmaf(wb, v1.w, oc[7]);
      oa[8]  = fmaf(wa, v2.x, oa[8]);   oc[8]  = fmaf(wb, v2.x, oc[8]);
      oa[9]  = fmaf(wa, v2.y, oa[9]);   oc[9]  = fmaf(wb, v2.y, oc[9]);
      oa[10] = fmaf(wa, v2.z, oa[10]);  oc[10] = fmaf(wb, v2.z, oc[10]);
      oa[11] = fmaf(wa, v2.w, oa[11]);  oc[11] = fmaf(wb, v2.w, oc[11]);
      oa[12] = fmaf(wa, v3.x, oa[12]);  oc[12] = fmaf(wb, v3.x, oc[12]);
      oa[13] = fmaf(wa, v3.y, oa[13]);  oc[13] = fmaf(wb, v3.y, oc[13]);
      oa[14] = fmaf(wa, v3.z, oa[14]);  oc[14] = fmaf(wb, v3.z, oc[14]);
      oa[15] = fmaf(wa, v3.w, oa[15]);  oc[15] = fmaf(wb, v3.w, oc[15]);
    }
  }
  const float inva = 1.f / sa, invb = 1.f / sb;
  if (na < NPER){
    short8 s0, s1;
    #pragma unroll
    for (int i = 0; i < 8; i++){
      s0[i] = (short)f2bf(oa[i] * inva);
      s1[i] = (short)f2bf(oa[8 + i] * inva);
    }
    unsigned short* op = ob + ((size_t)b * NPER + na) * C + h * 16;
    *reinterpret_cast<short8*>(op) = s0;
    *reinterpret_cast<short8*>(op + 8) = s1;
  }
  if (nb < NPER){
    short8 s0, s1;
    #pragma unroll
    for (int i = 0; i < 8; i++){
      s0[i] = (short)f2bf(oc[i] * invb);
      s1[i] = (short)f2bf(oc[8 + i] * invb);
    }
    unsigned short* op = ob + ((size_t)b * NPER + nb) * C + h * 16;
    *reinterpret_cast<short8*>(op) = s0;
    *reinterpret_cast<short8*>(op + 8) = s1;
  }
}

extern "C" void kernel_launch(void* const* d_in, const int* in_sizes, int n_in,
                              void* d_out, int out_size, void* d_ws, size_t ws_size,
                              hipStream_t stream){
  const float* feats  = (const float*)d_in[0];
  const float* probs  = (const float*)d_in[1];
  const float* convw  = (const float*)d_in[2];
  const float* gamma  = (const float*)d_in[3];
  const float* beta   = (const float*)d_in[4];
  const float* inw    = (const float*)d_in[5];
  const float* inb    = (const float*)d_in[6];
  const float* outw   = (const float*)d_in[7];
  const float* outb   = (const float*)d_in[8];
  const float* bw     = (const float*)d_in[9];
  const int*   coords = (const int*)d_in[10];
  const int N = in_sizes[0] / C;
  const int NPER = N / NB;
  const int NBLK = (N + 63) / 64;

  char* ws = (char*)d_ws;
  size_t off = 0;
  auto alloc = [&](size_t bytes) -> char* {
    char* r = ws + off; off += (bytes + 255) & ~(size_t)255; return r;
  };
  int* grid_h            = (int*)alloc((size_t)NB * GRID3 * 4);          // 33.5 MB (no memset)
  unsigned short* featsb = (unsigned short*)alloc((size_t)N * C * 2);    // 25.6 MB
  unsigned short* convwt = (unsigned short*)alloc((size_t)27 * C * C * 2);
  unsigned short* wq     = (unsigned short*)alloc((size_t)C * C * 2);
  unsigned short* wkvT   = (unsigned short*)alloc((size_t)2 * C * C * 2);
  unsigned short* w2b    = (unsigned short*)alloc((size_t)C * C * 2);
  float* b2              = (float*)alloc(512);
  float* xconv           = (float*)alloc((size_t)N * C * 4);             // 51.2 MB
  unsigned short* qb     = (unsigned short*)alloc((size_t)N * C * 2);    // 25.6 MB
  unsigned short* xb     = (unsigned short*)alloc((size_t)N * C * 2);    // 25.6 MB BN+ReLU(x) bf16
  int2* pairs            = (int2*)alloc((size_t)27 * PCAP * 8);          // 1.7 MB
  float* spgs            = (float*)alloc((size_t)STAT_BLK * 256 * 4);    // 1 MB
  float* dpart           = (float*)alloc((size_t)DEN_BLK * 128 * 4);     // 0.5 MB
  float* zero_base       = (float*)alloc((size_t)512 * 4);
  float* gsum   = zero_base;
  float* gsq    = zero_base + 128;
  float* denom  = zero_base + 256;
  int*   gcnt   = (int*)(zero_base + 384);
  float* invden = (float*)alloc(512);
  float* scalev = (float*)alloc(512);
  float* shiftv = (float*)alloc(512);
  float* kh     = (float*)alloc((size_t)NB * KSLOT * C * 4);
  float* vh     = (float*)alloc((size_t)NB * KSLOT * C * 4);
  // aliases (lifetimes disjoint):
  float* pbuf = (float*)grid_h;                  // grid dead after pairk; 16.8 <= 33.5 MB OK
  unsigned short* o_bf = featsb;                 // featsb dead after scatk

  (void)hipMemsetAsync(zero_base, 0, (size_t)512 * 4, stream);
  prepk<<<PREP_BLKS + 128, 256, 0, stream>>>(feats, convw, inw, coords, bw, outw, outb,
                                             featsb, convwt, wq, wkvT, grid_h, w2b, b2,
                                             (long)N * C);
  pairk<<<(N + 255) / 256, 256, 0, stream>>>(coords, grid_h, pairs, gcnt, N);
  // grid_h dead; pbuf aliases it
  gemm128<<<NBLK, 256, 0, stream>>>(featsb, convwt + 13 * C * C, nullptr, 1.f, xconv, nullptr, N);
  scatk<<<dim3(26, 32), 256, 0, stream>>>(featsb, convwt, pairs, gcnt, xconv, N);
  sdk<<<STAT_BLK + DEN_BLK, 256, 0, stream>>>(xconv, probs, coords, spgs, dpart, N);
  {
    dim3 rg(3, 8);
    reduk<<<rg, 128, 0, stream>>>(spgs, dpart, gsum, gsq, denom);
  }
  finalizek<<<1, 128, 0, stream>>>(gsum, gsq, gamma, beta, denom, scalev, shiftv, invden, N);
  ctx2k<<<NB * CTX_BPB, 256, 0, stream>>>(xconv, probs, scalev, shiftv, pbuf, xb, NPER);
  kvk<<<NB * KSLOT, 256, 0, stream>>>(pbuf, invden, wkvT, inb, kh, vh);
  gemm128<<<NBLK, 256, 0, stream>>>(xb, wq, inb, 0.25f, nullptr, qb, N);
  dim3 agrid((NPER + 63) / 64, NB);
  attn5k<<<agrid, 256, 0, stream>>>(qb, kh, vh, o_bf, NPER);
  gemm128<<<NBLK, 256, 0, stream>>>(o_bf, w2b, b2, 1.f, (float*)d_out, nullptr, N);
}

// Round 8
// 418.345 us; speedup vs baseline: 1.1679x; 1.0232x over previous
//
#include <hip/hip_runtime.h>
#include <hip/hip_bf16.h>

typedef __attribute__((ext_vector_type(8))) short short8;
typedef __attribute__((ext_vector_type(4))) float floatx4;

#define NB 4
#define GRIDD 128
#define GRID3 (128*128*128)
#define C 128
#define KSLOT 32
#define CTX_BPB 256
#define STAT_BLK 1024
#define PCAP 8192
#define PREP_BLKS 2048

static __device__ __forceinline__ unsigned short f2bf(float f){
  unsigned u = __builtin_bit_cast(unsigned, f);
  unsigned r = (u + 0x7FFFu + ((u >> 16) & 1u)) >> 16;
  return (unsigned short)r;
}
static __device__ __forceinline__ float bf2f(unsigned short h){
  unsigned u = ((unsigned)h) << 16;
  return __builtin_bit_cast(float, u);
}

// ---------- prep: bf16 conversions + transposes + grid-hash scatter + w2 fold ----------
__global__ void prepk(const float* __restrict__ feats, const float* __restrict__ convw,
                      const float* __restrict__ inw, const int* __restrict__ coords,
                      const float* __restrict__ bw, const float* __restrict__ outw,
                      const float* __restrict__ outb,
                      unsigned short* __restrict__ Fb, unsigned short* __restrict__ Wt,
                      unsigned short* __restrict__ Wq, unsigned short* __restrict__ WkvT,
                      int* __restrict__ gh, unsigned short* __restrict__ W2b,
                      float* __restrict__ b2, long total1)
{
  const int t = threadIdx.x;
  if (blockIdx.x >= PREP_BLKS){
    __shared__ float wcf[128];
    __shared__ float red[128];
    const int o = blockIdx.x - PREP_BLKS;
    if (t < 128){
      const float w_i = bw[(size_t)o*256 + t] + bw[(size_t)o*256 + 128 + t];
      wcf[t] = w_i;
      red[t] = w_i * outb[t];
    }
    __syncthreads();
    if (t < 128){
      float acc = 0.f;
      #pragma unroll 8
      for (int j = 0; j < 128; j++) acc = fmaf(wcf[j], outw[j*128 + t], acc);
      W2b[o*128 + t] = f2bf(acc);
    }
    for (int s = 64; s > 0; s >>= 1){
      if (t < s) red[t] += red[t + s];
      __syncthreads();
    }
    if (t == 0) b2[o] = red[0];
    return;
  }
  const long stride = (long)PREP_BLKS * blockDim.x;
  const long i0 = (long)blockIdx.x * blockDim.x + t;
  const long q4 = total1 >> 2;
  const float4* f4 = reinterpret_cast<const float4*>(feats);
  ushort4* fb4 = reinterpret_cast<ushort4*>(Fb);
  for (long i = i0; i < q4; i += stride){
    const float4 v = f4[i];
    ushort4 o; o.x = f2bf(v.x); o.y = f2bf(v.y); o.z = f2bf(v.z); o.w = f2bf(v.w);
    fb4[i] = o;
  }
  for (long i = i0; i < 27L*C*C; i += stride){
    long k = i >> 14; long r = (i >> 7) & 127; long c = i & 127;
    Wt[i] = f2bf(convw[(k << 14) + (c << 7) + r]);
  }
  for (long i = i0; i < C*C; i += stride) Wq[i] = f2bf(inw[i]);
  for (long i = i0; i < 2L*C*C; i += stride){
    long which = i >> 14, rem = i & 16383, ii = rem >> 7, cout = rem & 127;
    WkvT[i] = f2bf(inw[((1 + which) << 14) + (cout << 7) + ii]);
  }
  const long nsites = total1 >> 7;
  for (long i = i0; i < nsites; i += stride){
    const int4 cr = *reinterpret_cast<const int4*>(coords + i * 4);
    gh[(((cr.x*GRIDD + cr.y)*GRIDD + cr.z)*GRIDD) + cr.w] = (int)i;
  }
}

// ---------- pair lists; coords-validated (garbage-proof), wave-aggregated counts ----------
__global__ __launch_bounds__(256) void pairk(const int* __restrict__ coords,
                                             const int* __restrict__ gh,
                                             int2* __restrict__ pairs,
                                             int* __restrict__ gcnt, int N){
  __shared__ int wcnt[4][27];
  __shared__ int woff[4][27];
  const int t = threadIdx.x, wave = t >> 6, lane = t & 63;
  const int p = blockIdx.x * 256 + t;
  const bool active = p < N;
  int4 cr = make_int4(0, 0, 0, 0);
  if (active) cr = *reinterpret_cast<const int4*>(coords + (size_t)p * 4);
  const int b = cr.x, x = cr.y, y = cr.z, z = cr.w;
  int jl[27];
  #pragma unroll
  for (int k = 0; k < 27; k++){
    jl[k] = -1;
    if (k == 13) continue;
    if (active){
      const int dx = k / 9 - 1, dy = (k / 3) % 3 - 1, dz = k % 3 - 1;
      const int nx = x + dx, ny = y + dy, nz = z + dz;
      if (((unsigned)nx < 128u) & ((unsigned)ny < 128u) & ((unsigned)nz < 128u)){
        const int gi = ((((b << 7) + nx) << 7) + ny) * GRIDD + nz;
        const int jj = gh[gi];
        if ((unsigned)jj < (unsigned)N){
          const int4 cj = *reinterpret_cast<const int4*>(coords + (size_t)jj * 4);
          if (cj.x == b && cj.y == nx && cj.z == ny && cj.w == nz) jl[k] = jj;
        }
      }
    }
  }
  #pragma unroll
  for (int k = 0; k < 27; k++){
    const unsigned long long m = __ballot(jl[k] >= 0);
    if (lane == 0) wcnt[wave][k] = (int)__popcll(m);
  }
  __syncthreads();
  if (t < 27){
    const int c0 = wcnt[0][t], c1 = wcnt[1][t], c2 = wcnt[2][t], c3 = wcnt[3][t];
    const int tot = c0 + c1 + c2 + c3;
    int gb = 0;
    if (t != 13 && tot > 0) gb = atomicAdd(&gcnt[t], tot);
    woff[0][t] = gb;
    woff[1][t] = gb + c0;
    woff[2][t] = gb + c0 + c1;
    woff[3][t] = gb + c0 + c1 + c2;
  }
  __syncthreads();
  const unsigned long long ltm = ((unsigned long long)1 << lane) - 1;
  #pragma unroll
  for (int k = 0; k < 27; k++){
    if (k == 13) continue;
    const unsigned long long m = __ballot(jl[k] >= 0);
    if (jl[k] >= 0){
      const int slot = woff[wave][k] + (int)__popcll(m & ltm);
      if (slot < PCAP) pairs[(size_t)k * PCAP + slot] = make_int2(p, jl[k]);
    }
  }
}

// ---------- off-center scatter-GEMM: Wt[k] in LDS, 16-pair chunks, atomic adds ----------
__global__ __launch_bounds__(256) void scatk(
    const unsigned short* __restrict__ F, const unsigned short* __restrict__ Wt,
    const int2* __restrict__ pairs, const int* __restrict__ gcnt,
    float* __restrict__ X, int N)
{
  __shared__ unsigned short wl[128 * 136];
  const int k = (blockIdx.x < 13) ? blockIdx.x : blockIdx.x + 1;
  const int t = threadIdx.x;
  const unsigned short* wg = Wt + (size_t)k * C * C;
  for (int idx = t; idx < 128 * 16; idx += 256){
    const int row = idx >> 4, seg = idx & 15;
    *reinterpret_cast<short8*>(&wl[row * 136 + seg * 8]) =
        *reinterpret_cast<const short8*>(wg + row * 128 + seg * 8);
  }
  __syncthreads();
  const int cnt = min(gcnt[k], PCAP);
  const int nch = (cnt + 15) >> 4;
  const int wave = t >> 6, lane = t & 63, lo = lane & 15, hi = lane >> 4;
  for (int c = blockIdx.y * 4 + wave; c < nch; c += 32 * 4){
    const int pidx = c * 16 + lo;
    const bool pv = pidx < cnt;
    const int2 pr = pv ? pairs[(size_t)k * PCAP + pidx] : make_int2(0, 0);
    const unsigned short* frow = F + (size_t)pr.y * C;
    short8 a[4];
    #pragma unroll
    for (int kc = 0; kc < 4; kc++){
      a[kc] = *reinterpret_cast<const short8*>(frow + kc * 32 + hi * 8);
      if (!pv) a[kc] = (short8){0,0,0,0,0,0,0,0};
    }
    floatx4 acc[8];
    #pragma unroll
    for (int i = 0; i < 8; i++) acc[i] = (floatx4){0.f,0.f,0.f,0.f};
    #pragma unroll
    for (int kc = 0; kc < 4; kc++){
      const int koff = kc * 32 + hi * 8;
      #pragma unroll
      for (int ct = 0; ct < 8; ct++){
        const short8 b = *reinterpret_cast<const short8*>(&wl[(ct*16 + lo) * 136 + koff]);
        acc[ct] = __builtin_amdgcn_mfma_f32_16x16x32_bf16(a[kc], b, acc[ct], 0, 0, 0);
      }
    }
    #pragma unroll
    for (int i2 = 0; i2 < 4; i2++){
      const int src = hi * 4 + i2;
      const int row = __shfl(pr.x, src);
      if (c * 16 + src < cnt){
        #pragma unroll
        for (int ct = 0; ct < 8; ct++)
          atomicAdd(&X[(size_t)row * C + ct * 16 + lo], acc[ct][i2]);
      }
    }
  }
}

// ---------- BN stat partials over f32 xconv ----------
__global__ __launch_bounds__(256) void sdk(const float* __restrict__ X,
                                           float* __restrict__ spgs, int N){
  __shared__ float ls[256][4];
  __shared__ float lq[256][4];
  const int t = threadIdx.x;
  const int blk = blockIdx.x;
  const int c4 = t & 31, rg = t >> 5;
  float s0=0.f,s1=0.f,s2=0.f,s3=0.f, q0=0.f,q1=0.f,q2=0.f,q3=0.f;
  for (int r = blk * 8 + rg; r < N; r += STAT_BLK * 8){
    const float4 v = *reinterpret_cast<const float4*>(X + (size_t)r * C + c4 * 4);
    s0 += v.x; s1 += v.y; s2 += v.z; s3 += v.w;
    q0 = fmaf(v.x, v.x, q0); q1 = fmaf(v.y, v.y, q1);
    q2 = fmaf(v.z, v.z, q2); q3 = fmaf(v.w, v.w, q3);
  }
  ls[t][0]=s0; ls[t][1]=s1; ls[t][2]=s2; ls[t][3]=s3;
  lq[t][0]=q0; lq[t][1]=q1; lq[t][2]=q2; lq[t][3]=q3;
  __syncthreads();
  if (t < 32){
    float as[4]={0.f,0.f,0.f,0.f}, aq[4]={0.f,0.f,0.f,0.f};
    #pragma unroll
    for (int g = 0; g < 8; g++){
      #pragma unroll
      for (int j = 0; j < 4; j++){ as[j] += ls[g*32 + t][j]; aq[j] += lq[g*32 + t][j]; }
    }
    #pragma unroll
    for (int j = 0; j < 4; j++){
      spgs[(size_t)blk * 256 + t*4 + j] = as[j];
      spgs[(size_t)blk * 256 + 128 + t*4 + j] = aq[j];
    }
  }
}

// ---------- reduce stat partials + last-block finalize (BN scale/shift) ----------
__global__ __launch_bounds__(128) void reduk(const float* __restrict__ pgs,
                                             float* __restrict__ gsum,
                                             float* __restrict__ gsq,
                                             const float* __restrict__ gamma,
                                             const float* __restrict__ beta,
                                             float* __restrict__ scalev,
                                             float* __restrict__ shiftv,
                                             int* __restrict__ cnt, int N){
  const int which = blockIdx.x, slice = blockIdx.y, t = threadIdx.x;
  const float* src = pgs + which * 128 + t;
  float s = 0.f;
  for (int j = slice; j < STAT_BLK; j += 8) s += src[(size_t)j * 256];
  atomicAdd((which ? gsq : gsum) + t, s);
  __threadfence();
  __syncthreads();
  __shared__ int last;
  if (t == 0) last = (atomicAdd(cnt, 1) == 15);
  __syncthreads();
  if (last){
    // coherent re-reads of the device-scope accumulators
    const float gs = atomicAdd(gsum + t, 0.f);
    const float gq = atomicAdd(gsq + t, 0.f);
    const float invN = 1.f / (float)N;
    const float mu = gs * invN;
    const float var = gq * invN - mu * mu;
    const float sc = gamma[t] * rsqrtf(var + 1e-5f);
    scalev[t] = sc;
    shiftv[t] = beta[t] - mu * sc;
  }
}

// ---------- ctx partials v4: LDS tiles + BN+ReLU + xb bf16 + denom partials ----------
__global__ __launch_bounds__(256) void ctx2k(const float* __restrict__ Xm,
                                             const float* __restrict__ probs,
                                             const float* __restrict__ scalev,
                                             const float* __restrict__ shiftv,
                                             float* __restrict__ pbuf,
                                             unsigned short* __restrict__ xb,
                                             float* __restrict__ dpart2, int NPER){
  __shared__ float xL[32 * 128];       // 16 KB raw x tile
  __shared__ float pe[32 * 32];        // 4 KB exp(probs) tile
  __shared__ float red[2 * KSLOT * C]; // 32 KB reduction
  __shared__ float scL[128], shL[128]; // 1 KB BN params
  const int blk = blockIdx.x;
  const int b = blk >> 8, j = blk & 255;
  const int rows = (NPER + CTX_BPB - 1) / CTX_BPB;
  const int r0 = j * rows;
  const int r1 = min(r0 + rows, NPER);
  const int t = threadIdx.x, c = t & 127, rh = t >> 7;
  if (t < 128){ scL[t] = scalev[t]; shL[t] = shiftv[t]; }
  __syncthreads();
  const float sc = scL[c], sh = shL[c];
  float acc[KSLOT];
  #pragma unroll
  for (int k = 0; k < KSLOT; k++) acc[k] = 0.f;
  const int dk = t & 31, dg = t >> 5;   // denom lanes: k slot, row group
  float dsum = 0.f;

  const int wr = t >> 3;            // tile row 0..31
  const int wc = (t & 7) * 16;      // col start 0..112

  for (int base = r0; base < r1; base += 32){
    __syncthreads();
    #pragma unroll
    for (int i = 0; i < 4; i++){
      const int idx = i * 256 + t;
      const int r = idx >> 5, c4 = idx & 31;
      const int rr = base + r;
      float4 v = make_float4(0.f, 0.f, 0.f, 0.f);
      if (rr < r1) v = *reinterpret_cast<const float4*>(Xm + ((size_t)b * NPER + rr) * C + c4 * 4);
      *reinterpret_cast<float4*>(&xL[r * 128 + c4 * 4]) = v;
    }
    {
      const int r = t >> 3, k4 = t & 7;
      const int rr = base + r;
      float4 v = make_float4(0.f, 0.f, 0.f, 0.f);
      if (rr < r1){
        const float4 pv = *reinterpret_cast<const float4*>(probs + ((size_t)b * NPER + rr) * 32 + k4 * 4);
        v.x = __expf(pv.x); v.y = __expf(pv.y); v.z = __expf(pv.z); v.w = __expf(pv.w);
      }
      *reinterpret_cast<float4*>(&pe[r * 32 + k4 * 4]) = v;
    }
    __syncthreads();
    {
      const int rr = base + wr;
      if (rr < r1){
        short8 o0, o1;
        #pragma unroll
        for (int jj = 0; jj < 8; jj++){
          o0[jj] = (short)f2bf(fmaxf(fmaf(xL[wr * 128 + wc + jj], scL[wc + jj], shL[wc + jj]), 0.f));
          o1[jj] = (short)f2bf(fmaxf(fmaf(xL[wr * 128 + wc + 8 + jj], scL[wc + 8 + jj], shL[wc + 8 + jj]), 0.f));
        }
        unsigned short* xp = xb + ((size_t)b * NPER + rr) * C + wc;
        *reinterpret_cast<short8*>(xp) = o0;
        *reinterpret_cast<short8*>(xp + 8) = o1;
      }
    }
    // denom partials: rows beyond r1 staged as 0
    #pragma unroll
    for (int rr4 = 0; rr4 < 4; rr4++) dsum += pe[(dg + rr4 * 8) * 32 + dk];
    const int rend = min(32, r1 - base);
    for (int r = rh; r < rend; r += 2){
      const float xv = fmaxf(fmaf(xL[r * 128 + c], sc, sh), 0.f);
      const float4* wrp = reinterpret_cast<const float4*>(&pe[r * 32]);
      #pragma unroll
      for (int kq = 0; kq < 8; kq++){
        const float4 w4 = wrp[kq];   // wave-broadcast (same addr all lanes)
        acc[kq*4+0] = fmaf(w4.x, xv, acc[kq*4+0]);
        acc[kq*4+1] = fmaf(w4.y, xv, acc[kq*4+1]);
        acc[kq*4+2] = fmaf(w4.z, xv, acc[kq*4+2]);
        acc[kq*4+3] = fmaf(w4.w, xv, acc[kq*4+3]);
      }
    }
  }
  __syncthreads();
  #pragma unroll
  for (int k = 0; k < KSLOT; k++) red[(rh * KSLOT + k) * C + c] = acc[k];
  pe[dg * 32 + dk] = dsum;           // pe free after last tile
  __syncthreads();
  float* dst = pbuf + (size_t)blk * KSLOT * C;
  for (int i = t; i < KSLOT * C; i += 256) dst[i] = red[i] + red[KSLOT * C + i];
  if (t < 32){
    float s = 0.f;
    #pragma unroll
    for (int g = 0; g < 8; g++) s += pe[g * 32 + t];
    dpart2[(size_t)t * (NB * CTX_BPB) + blk] = s;   // [32][1024], coalesced read in kvk
  }
}

// ---------- kv: reduce ctx partials + denom, then project ----------
__global__ __launch_bounds__(256) void kvk(const float* __restrict__ pbuf,
                                           const float* __restrict__ dpart2,
                                           const unsigned short* __restrict__ WkvT,
                                           const float* __restrict__ inb,
                                           float* __restrict__ kh, float* __restrict__ vh){
  __shared__ float rowp[2][C];
  __shared__ float row[C];
  __shared__ float dred[256];
  const int bk = blockIdx.x;              // b*32 + k
  const int b = bk >> 5, k = bk & 31;
  const int t = threadIdx.x, c = t & 127, jh = t >> 7;
  dred[t] = dpart2[(size_t)k * (NB * CTX_BPB) + b * CTX_BPB + t];
  float s = 0.f;
  for (int j = jh; j < CTX_BPB; j += 2)
    s += pbuf[((size_t)(b * CTX_BPB + j) * KSLOT + k) * C + c];
  rowp[jh][c] = s;
  __syncthreads();
  for (int sred = 128; sred > 0; sred >>= 1){
    if (t < sred) dred[t] += dred[t + sred];
    __syncthreads();
  }
  const float invden = 1.f / dred[0];
  if (t < C) row[t] = (rowp[0][t] + rowp[1][t]) * invden;
  __syncthreads();
  const int which = t >> 7;
  const unsigned short* W = WkvT + (size_t)which * C * C;
  float acc = inb[(1 + which) * C + c];
  #pragma unroll 8
  for (int i = 0; i < C; i++) acc = fmaf(row[i], bf2f(W[i * C + c]), acc);
  (which ? vh : kh)[(size_t)bk * C + c] = acc;
}

// ---------- N x 128 @ (128x128)^T bf16 MFMA GEMM (swapped operands: vectorized stores) ----------
__global__ __launch_bounds__(256) void gemm128(
    const unsigned short* __restrict__ A, const unsigned short* __restrict__ W,
    const float* __restrict__ bias, float scale,
    float* __restrict__ outF, unsigned short* __restrict__ outB, int N)
{
  const int tid = threadIdx.x;
  const int wave = tid >> 6, lane = tid & 63;
  const int rbase = blockIdx.x * 64 + (wave >> 1) * 32;
  const int cbase = (wave & 1) * 64;
  const int lo = lane & 15, hi = lane >> 4;
  floatx4 acc[2][4];
  #pragma unroll
  for (int rt = 0; rt < 2; rt++)
    #pragma unroll
    for (int ct = 0; ct < 4; ct++) acc[rt][ct] = (floatx4){0.f,0.f,0.f,0.f};
  const int m0 = rbase + lo, m1 = rbase + 16 + lo;
  const int m0c = m0 < N ? m0 : N - 1;
  const int m1c = m1 < N ? m1 : N - 1;
  #pragma unroll
  for (int kc = 0; kc < 4; kc++){
    const int koff = kc * 32 + hi * 8;
    const short8 a0 = *reinterpret_cast<const short8*>(A + (size_t)m0c * C + koff);
    const short8 a1 = *reinterpret_cast<const short8*>(A + (size_t)m1c * C + koff);
    #pragma unroll
    for (int ct = 0; ct < 4; ct++){
      const int n = cbase + ct * 16 + lo;
      const short8 b = *reinterpret_cast<const short8*>(W + (size_t)n * C + koff);
      acc[0][ct] = __builtin_amdgcn_mfma_f32_16x16x32_bf16(b, a0, acc[0][ct], 0, 0, 0);
      acc[1][ct] = __builtin_amdgcn_mfma_f32_16x16x32_bf16(b, a1, acc[1][ct], 0, 0, 0);
    }
  }
  #pragma unroll
  for (int rt = 0; rt < 2; rt++){
    const int row = rbase + rt * 16 + lo;
    if (row < N){
      #pragma unroll
      for (int ct = 0; ct < 4; ct++){
        const int col = cbase + ct * 16 + hi * 4;
        float4 bv = make_float4(0.f, 0.f, 0.f, 0.f);
        if (bias) bv = *reinterpret_cast<const float4*>(bias + col);
        float4 v;
        v.x = (acc[rt][ct][0] + bv.x) * scale;
        v.y = (acc[rt][ct][1] + bv.y) * scale;
        v.z = (acc[rt][ct][2] + bv.z) * scale;
        v.w = (acc[rt][ct][3] + bv.w) * scale;
        if (outF) *reinterpret_cast<float4*>(outF + (size_t)row * C + col) = v;
        if (outB){
          ushort4 u;
          u.x = f2bf(v.x); u.y = f2bf(v.y); u.z = f2bf(v.z); u.w = f2bf(v.w);
          *reinterpret_cast<ushort4*>(outB + (size_t)row * C + col) = u;
        }
      }
    }
  }
}

// ---------- attention v6: q-proj (MFMA -> qL) + v5 online-softmax attention ----------
// Two phases, one __syncthreads; 49.4 KB LDS (3 blocks/CU); K/V staging latency
// hidden under q-phase MFMA.
__global__ __launch_bounds__(256) void attn6k(const unsigned short* __restrict__ xb,
                                              const unsigned short* __restrict__ wq,
                                              const float* __restrict__ inb,
                                              const float* __restrict__ kh,
                                              const float* __restrict__ vh,
                                              unsigned short* __restrict__ ob, int NPER){
  __shared__ float khL[KSLOT * C];          // 16 KB
  __shared__ float vhL[KSLOT * C];          // 16 KB
  __shared__ unsigned short qL[64 * 136];   // 17 KB (pad 136)
  const int t = threadIdx.x;
  const int b = blockIdx.y;
  const int n0 = blockIdx.x * 64;
  // stage K/V (loads issue first; latency hides under q-phase)
  {
    const float4* ks = reinterpret_cast<const float4*>(kh + (size_t)b * KSLOT * C);
    const float4* vs = reinterpret_cast<const float4*>(vh + (size_t)b * KSLOT * C);
    float4* kd = reinterpret_cast<float4*>(khL);
    float4* vd = reinterpret_cast<float4*>(vhL);
    #pragma unroll
    for (int i = 0; i < 4; i++){ kd[i * 256 + t] = ks[i * 256 + t]; vd[i * 256 + t] = vs[i * 256 + t]; }
  }
  // q phase: q = (xb @ Wq^T + bq) * 0.25 -> qL (proven gemm128 pattern)
  const int wave = t >> 6, lane = t & 63;
  const int rb = (wave >> 1) * 32, cb = (wave & 1) * 64;
  const int lo = lane & 15, hi = lane >> 4;
  {
    floatx4 qa2[2][4];
    #pragma unroll
    for (int rt = 0; rt < 2; rt++)
      #pragma unroll
      for (int ct = 0; ct < 4; ct++) qa2[rt][ct] = (floatx4){0.f,0.f,0.f,0.f};
    const unsigned short* A = xb + (size_t)b * NPER * C;
    const int m0 = n0 + rb + lo, m1 = n0 + rb + 16 + lo;
    const int m0c = m0 < NPER ? m0 : NPER - 1;
    const int m1c = m1 < NPER ? m1 : NPER - 1;
    #pragma unroll
    for (int kc = 0; kc < 4; kc++){
      const int koff = kc * 32 + hi * 8;
      const short8 a0 = *reinterpret_cast<const short8*>(A + (size_t)m0c * C + koff);
      const short8 a1 = *reinterpret_cast<const short8*>(A + (size_t)m1c * C + koff);
      #pragma unroll
      for (int ct = 0; ct < 4; ct++){
        const int n = cb + ct * 16 + lo;
        const short8 w = *reinterpret_cast<const short8*>(wq + (size_t)n * C + koff);
        qa2[0][ct] = __builtin_amdgcn_mfma_f32_16x16x32_bf16(w, a0, qa2[0][ct], 0, 0, 0);
        qa2[1][ct] = __builtin_amdgcn_mfma_f32_16x16x32_bf16(w, a1, qa2[1][ct], 0, 0, 0);
      }
    }
    #pragma unroll
    for (int rt = 0; rt < 2; rt++){
      const int row = rb + rt * 16 + lo;
      #pragma unroll
      for (int ct = 0; ct < 4; ct++){
        const int col = cb + ct * 16 + hi * 4;
        const float4 bv = *reinterpret_cast<const float4*>(inb + col);
        ushort4 u;
        u.x = f2bf((qa2[rt][ct][0] + bv.x) * 0.25f);
        u.y = f2bf((qa2[rt][ct][1] + bv.y) * 0.25f);
        u.z = f2bf((qa2[rt][ct][2] + bv.z) * 0.25f);
        u.w = f2bf((qa2[rt][ct][3] + bv.w) * 0.25f);
        *reinterpret_cast<ushort4*>(&qL[row * 136 + col]) = u;
      }
    }
  }
  __syncthreads();
  // attention phase (v5 body; q from qL)
  const int h = t >> 5, p = t & 31;
  const int na = n0 + p, nb2 = n0 + 32 + p;
  float qa[16], qc[16];
  {
    const short8* qpa = reinterpret_cast<const short8*>(&qL[p * 136 + h * 16]);
    const short8* qpb = reinterpret_cast<const short8*>(&qL[(32 + p) * 136 + h * 16]);
    const short8 a0 = qpa[0], a1 = qpa[1];
    const short8 b0 = qpb[0], b1 = qpb[1];
    #pragma unroll
    for (int i = 0; i < 8; i++){
      qa[i]     = bf2f((unsigned short)a0[i]);
      qa[8 + i] = bf2f((unsigned short)a1[i]);
      qc[i]     = bf2f((unsigned short)b0[i]);
      qc[8 + i] = bf2f((unsigned short)b1[i]);
    }
  }
  float ma = -3.0e38f, mb = -3.0e38f;
  float sa = 0.f, sb = 0.f;
  float oa[16], oc[16];
  #pragma unroll
  for (int i = 0; i < 16; i++){ oa[i] = 0.f; oc[i] = 0.f; }
  for (int tau = 0; tau < 4; tau++){
    float va[8], vb[8];
    #pragma unroll
    for (int kk = 0; kk < 8; kk++){
      const int k = tau * 8 + kk;
      const float4* kp = reinterpret_cast<const float4*>(&khL[k * C + h * 16]);
      const float4 k0 = kp[0], k1 = kp[1], k2 = kp[2], k3 = kp[3];
      float x, y;
      x = qa[0] * k0.x;            y = qc[0] * k0.x;
      x = fmaf(qa[1],  k0.y, x);   y = fmaf(qc[1],  k0.y, y);
      x = fmaf(qa[2],  k0.z, x);   y = fmaf(qc[2],  k0.z, y);
      x = fmaf(qa[3],  k0.w, x);   y = fmaf(qc[3],  k0.w, y);
      x = fmaf(qa[4],  k1.x, x);   y = fmaf(qc[4],  k1.x, y);
      x = fmaf(qa[5],  k1.y, x);   y = fmaf(qc[5],  k1.y, y);
      x = fmaf(qa[6],  k1.z, x);   y = fmaf(qc[6],  k1.z, y);
      x = fmaf(qa[7],  k1.w, x);   y = fmaf(qc[7],  k1.w, y);
      x = fmaf(qa[8],  k2.x, x);   y = fmaf(qc[8],  k2.x, y);
      x = fmaf(qa[9],  k2.y, x);   y = fmaf(qc[9],  k2.y, y);
      x = fmaf(qa[10], k2.z, x);   y = fmaf(qc[10], k2.z, y);
      x = fmaf(qa[11], k2.w, x);   y = fmaf(qc[11], k2.w, y);
      x = fmaf(qa[12], k3.x, x);   y = fmaf(qc[12], k3.x, y);
      x = fmaf(qa[13], k3.y, x);   y = fmaf(qc[13], k3.y, y);
      x = fmaf(qa[14], k3.z, x);   y = fmaf(qc[14], k3.z, y);
      x = fmaf(qa[15], k3.w, x);   y = fmaf(qc[15], k3.w, y);
      va[kk] = x; vb[kk] = y;
    }
    float tma = va[0], tmb = vb[0];
    #pragma unroll
    for (int kk = 1; kk < 8; kk++){ tma = fmaxf(tma, va[kk]); tmb = fmaxf(tmb, vb[kk]); }
    const float ma2 = fmaxf(ma, tma), mb2 = fmaxf(mb, tmb);
    const float fa = __expf(ma - ma2), fb = __expf(mb - mb2);
    ma = ma2; mb = mb2;
    sa *= fa; sb *= fb;
    #pragma unroll
    for (int i = 0; i < 16; i++){ oa[i] *= fa; oc[i] *= fb; }
    #pragma unroll
    for (int kk = 0; kk < 8; kk++){
      const float ea = __expf(va[kk] - ma);
      const float eb = __expf(vb[kk] - mb);
      va[kk] = ea; vb[kk] = eb;
      sa += ea; sb += eb;
    }
    #pragma unroll
    for (int kk = 0; kk < 8; kk++){
      const int k = tau * 8 + kk;
      const float4* vp = reinterpret_cast<const float4*>(&vhL[k * C + h * 16]);
      const float4 v0 = vp[0], v1 = vp[1], v2 = vp[2], v3 = vp[3];
      const float wa = va[kk], wb = vb[kk];
      oa[0]  = fmaf(wa, v0.x, oa[0]);   oc[0]  = fmaf(wb, v0.x, oc[0]);
      oa[1]  = fmaf(wa, v0.y, oa[1]);   oc[1]  = fmaf(wb, v0.y, oc[1]);
      oa[2]  = fmaf(wa, v0.z, oa[2]);   oc[2]  = fmaf(wb, v0.z, oc[2]);
      oa[3]  = fmaf(wa, v0.w, oa[3]);   oc[3]  = fmaf(wb, v0.w, oc[3]);
      oa[4]  = fmaf(wa, v1.x, oa[4]);   oc[4]  = fmaf(wb, v1.x, oc[4]);
      oa[5]  = fmaf(wa, v1.y, oa[5]);   oc[5]  = fmaf(wb, v1.y, oc[5]);
      oa[6]  = fmaf(wa, v1.z, oa[6]);   oc[6]  = fmaf(wb, v1.z, oc[6]);
      oa[7]  = fmaf(wa, v1.w, oa[7]);   oc[7]  = fmaf(wb, v1.w, oc[7]);
      oa[8]  = fmaf(wa, v2.x, oa[8]);   oc[8]  = fmaf(wb, v2.x, oc[8]);
      oa[9]  = fmaf(wa, v2.y, oa[9]);   oc[9]  = fmaf(wb, v2.y, oc[9]);
      oa[10] = fmaf(wa, v2.z, oa[10]);  oc[10] = fmaf(wb, v2.z, oc[10]);
      oa[11] = fmaf(wa, v2.w, oa[11]);  oc[11] = fmaf(wb, v2.w, oc[11]);
      oa[12] = fmaf(wa, v3.x, oa[12]);  oc[12] = fmaf(wb, v3.x, oc[12]);
      oa[13] = fmaf(wa, v3.y, oa[13]);  oc[13] = fmaf(wb, v3.y, oc[13]);
      oa[14] = fmaf(wa, v3.z, oa[14]);  oc[14] = fmaf(wb, v3.z, oc[14]);
      oa[15] = fmaf(wa, v3.w, oa[15]);  oc[15] = fmaf(wb, v3.w, oc[15]);
    }
  }
  const float inva = 1.f / sa, invb = 1.f / sb;
  if (na < NPER){
    short8 s0, s1;
    #pragma unroll
    for (int i = 0; i < 8; i++){
      s0[i] = (short)f2bf(oa[i] * inva);
      s1[i] = (short)f2bf(oa[8 + i] * inva);
    }
    unsigned short* op = ob + ((size_t)b * NPER + na) * C + h * 16;
    *reinterpret_cast<short8*>(op) = s0;
    *reinterpret_cast<short8*>(op + 8) = s1;
  }
  if (nb2 < NPER){
    short8 s0, s1;
    #pragma unroll
    for (int i = 0; i < 8; i++){
      s0[i] = (short)f2bf(oc[i] * invb);
      s1[i] = (short)f2bf(oc[8 + i] * invb);
    }
    unsigned short* op = ob + ((size_t)b * NPER + nb2) * C + h * 16;
    *reinterpret_cast<short8*>(op) = s0;
    *reinterpret_cast<short8*>(op + 8) = s1;
  }
}

extern "C" void kernel_launch(void* const* d_in, const int* in_sizes, int n_in,
                              void* d_out, int out_size, void* d_ws, size_t ws_size,
                              hipStream_t stream){
  const float* feats  = (const float*)d_in[0];
  const float* probs  = (const float*)d_in[1];
  const float* convw  = (const float*)d_in[2];
  const float* gamma  = (const float*)d_in[3];
  const float* beta   = (const float*)d_in[4];
  const float* inw    = (const float*)d_in[5];
  const float* inb    = (const float*)d_in[6];
  const float* outw   = (const float*)d_in[7];
  const float* outb   = (const float*)d_in[8];
  const float* bw     = (const float*)d_in[9];
  const int*   coords = (const int*)d_in[10];
  const int N = in_sizes[0] / C;
  const int NPER = N / NB;
  const int NBLK = (N + 63) / 64;

  char* ws = (char*)d_ws;
  size_t off = 0;
  auto alloc = [&](size_t bytes) -> char* {
    char* r = ws + off; off += (bytes + 255) & ~(size_t)255; return r;
  };
  int* grid_h            = (int*)alloc((size_t)NB * GRID3 * 4);          // 33.5 MB (no memset)
  unsigned short* featsb = (unsigned short*)alloc((size_t)N * C * 2);    // 25.6 MB
  unsigned short* convwt = (unsigned short*)alloc((size_t)27 * C * C * 2);
  unsigned short* wq     = (unsigned short*)alloc((size_t)C * C * 2);
  unsigned short* wkvT   = (unsigned short*)alloc((size_t)2 * C * C * 2);
  unsigned short* w2b    = (unsigned short*)alloc((size_t)C * C * 2);
  float* b2              = (float*)alloc(512);
  float* xconv           = (float*)alloc((size_t)N * C * 4);             // 51.2 MB
  unsigned short* xb     = (unsigned short*)alloc((size_t)N * C * 2);    // 25.6 MB BN+ReLU(x) bf16
  int2* pairs            = (int2*)alloc((size_t)27 * PCAP * 8);          // 1.7 MB
  float* spgs            = (float*)alloc((size_t)STAT_BLK * 256 * 4);    // 1 MB
  float* dpart2          = (float*)alloc((size_t)32 * NB * CTX_BPB * 4); // 128 KB
  float* zero_base       = (float*)alloc((size_t)512 * 4);
  float* gsum   = zero_base;
  float* gsq    = zero_base + 128;
  int*   gcnt   = (int*)(zero_base + 256);
  int*   cnt    = (int*)(zero_base + 384);
  float* scalev = (float*)alloc(512);
  float* shiftv = (float*)alloc(512);
  float* kh     = (float*)alloc((size_t)NB * KSLOT * C * 4);
  float* vh     = (float*)alloc((size_t)NB * KSLOT * C * 4);
  // aliases (lifetimes disjoint):
  float* pbuf = (float*)grid_h;                  // grid dead after pairk; 16.8 <= 33.5 MB OK
  unsigned short* o_bf = featsb;                 // featsb dead after scatk

  (void)hipMemsetAsync(zero_base, 0, (size_t)512 * 4, stream);
  prepk<<<PREP_BLKS + 128, 256, 0, stream>>>(feats, convw, inw, coords, bw, outw, outb,
                                             featsb, convwt, wq, wkvT, grid_h, w2b, b2,
                                             (long)N * C);
  pairk<<<(N + 255) / 256, 256, 0, stream>>>(coords, grid_h, pairs, gcnt, N);
  // grid_h dead; pbuf aliases it
  gemm128<<<NBLK, 256, 0, stream>>>(featsb, convwt + 13 * C * C, nullptr, 1.f, xconv, nullptr, N);
  scatk<<<dim3(26, 32), 256, 0, stream>>>(featsb, convwt, pairs, gcnt, xconv, N);
  sdk<<<STAT_BLK, 256, 0, stream>>>(xconv, spgs, N);
  {
    dim3 rg(2, 8);
    reduk<<<rg, 128, 0, stream>>>(spgs, gsum, gsq, gamma, beta, scalev, shiftv, cnt, N);
  }
  ctx2k<<<NB * CTX_BPB, 256, 0, stream>>>(xconv, probs, scalev, shiftv, pbuf, xb, dpart2, NPER);
  kvk<<<NB * KSLOT, 256, 0, stream>>>(pbuf, dpart2, wkvT, inb, kh, vh);
  dim3 agrid((NPER + 63) / 64, NB);
  attn6k<<<agrid, 256, 0, stream>>>(xb, wq, inb, kh, vh, o_bf, NPER);
  gemm128<<<NBLK, 256, 0, stream>>>(o_bf, w2b, b2, 1.f, (float*)d_out, nullptr, N);
}